// Round 1
// baseline (670.580 us; speedup 1.0000x reference)
//
#include <hip/hip_runtime.h>
#include <math.h>

// Problem constants (from reference)
#define BATCH   8192
#define MROWS   16384      // 2*BATCH rows processed through the MLP
#define DIN     512
#define DH      256
#define DOUT    128
#define EPS_BN  1e-5f
#define TEMP    0.07f

using f4 = __attribute__((ext_vector_type(4))) float;

// ---------------------------------------------------------------------------
// Tiled fp32 GEMM with fused bias:  C[M x N] = A[M x K] @ W[K x N] + bias
// A rows come from A1 (rows < splitRow) or A2 (rows >= splitRow) so x1/x2 can
// be processed as one 16384-row batch. BM=128, BK=32, TM=8 fixed.
// TN in {4,8}; 256 threads arranged 16x16.
// ---------------------------------------------------------------------------
template <int BM, int BN, int TN, int K, int N, int NT>
__global__ __launch_bounds__(256) void gemm_bias(
    const float* __restrict__ A1, const float* __restrict__ A2, int splitRow,
    const float* __restrict__ Wm, const float* __restrict__ bias,
    float* __restrict__ C)
{
    constexpr int BK = 32;
    constexpr int AF4 = BM * BK / (4 * 256);   // float4 loads per thread (A)
    constexpr int BF4 = BN * BK / (4 * 256);   // float4 loads per thread (B)

    const int tid = threadIdx.x;
    const int tx = tid & 15;
    const int ty = tid >> 4;
    const int brow = blockIdx.y * BM;
    const int bcol = blockIdx.x * BN;

    __shared__ float As[BK][BM + 4];   // [k][row], padded: staging writes ~4-way max
    __shared__ float Bs[BK][BN];       // [k][col], linear

    f4 ra[AF4], rb[BF4];

    auto loadA = [&](int t) {
#pragma unroll
        for (int i = 0; i < AF4; ++i) {
            int l = i * 256 + tid;          // float4 index in BM x BK tile
            int row = l >> 3;               // 8 float4 per row (BK=32)
            int kq = (l & 7) << 2;
            int gr = brow + row;
            const float* src = (gr < splitRow) ? (A1 + (size_t)gr * K)
                                               : (A2 + (size_t)(gr - splitRow) * K);
            ra[i] = *(const f4*)(src + t * BK + kq);
        }
    };
    auto loadB = [&](int t) {
#pragma unroll
        for (int i = 0; i < BF4; ++i) {
            int l = i * 256 + tid;
            int row = l / (BN >> 2);
            int cq = (l % (BN >> 2)) << 2;
            rb[i] = *(const f4*)(Wm + (size_t)(t * BK + row) * N + bcol + cq);
        }
    };
    auto storeAB = [&]() {
#pragma unroll
        for (int i = 0; i < AF4; ++i) {
            int l = i * 256 + tid;
            int row = l >> 3;
            int kq = (l & 7) << 2;
            As[kq + 0][row] = ra[i][0];
            As[kq + 1][row] = ra[i][1];
            As[kq + 2][row] = ra[i][2];
            As[kq + 3][row] = ra[i][3];
        }
#pragma unroll
        for (int i = 0; i < BF4; ++i) {
            int l = i * 256 + tid;
            int row = l / (BN >> 2);
            int cq = (l % (BN >> 2)) << 2;
            *(f4*)&Bs[row][cq] = rb[i];
        }
    };

    float acc[8][TN] = {};

    loadA(0); loadB(0);
    storeAB();
    __syncthreads();

    for (int t = 0; t < NT; ++t) {
        const bool more = (t + 1 < NT);
        if (more) { loadA(t + 1); loadB(t + 1); }   // global loads in flight over compute
#pragma unroll
        for (int k = 0; k < BK; ++k) {
            f4 a0 = *(const f4*)&As[k][ty * 4];
            f4 a1 = *(const f4*)&As[k][ty * 4 + BM / 2];
            f4 b0 = *(const f4*)&Bs[k][tx * 4];
            f4 b1;
            if constexpr (TN == 8) b1 = *(const f4*)&Bs[k][tx * 4 + BN / 2];
#pragma unroll
            for (int j = 0; j < 4; ++j) {
#pragma unroll
                for (int c = 0; c < 4; ++c) {
                    acc[j][c]     = fmaf(a0[j], b0[c], acc[j][c]);
                    acc[4 + j][c] = fmaf(a1[j], b0[c], acc[4 + j][c]);
                    if constexpr (TN == 8) {
                        acc[j][4 + c]     = fmaf(a0[j], b1[c], acc[j][4 + c]);
                        acc[4 + j][4 + c] = fmaf(a1[j], b1[c], acc[4 + j][4 + c]);
                    }
                }
            }
        }
        __syncthreads();
        if (more) { storeAB(); __syncthreads(); }
    }

    // epilogue: + bias, coalesced float4 stores
    f4 b0v = *(const f4*)(bias + bcol + tx * 4);
    f4 b1v;
    if constexpr (TN == 8) b1v = *(const f4*)(bias + bcol + BN / 2 + tx * 4);
#pragma unroll
    for (int q = 0; q < 2; ++q) {
#pragma unroll
        for (int j = 0; j < 4; ++j) {
            int gr = brow + q * (BM / 2) + ty * 4 + j;
            f4 v, w;
#pragma unroll
            for (int c = 0; c < 4; ++c) v[c] = acc[q * 4 + j][c] + b0v[c];
            *(f4*)(C + (size_t)gr * N + bcol + tx * 4) = v;
            if constexpr (TN == 8) {
#pragma unroll
                for (int c = 0; c < 4; ++c) w[c] = acc[q * 4 + j][4 + c] + b1v[c];
                *(f4*)(C + (size_t)gr * N + bcol + BN / 2 + tx * 4) = w;
            }
        }
    }
}

// ---------------------------------------------------------------------------
// BN column stats (sum, sumsq) per half (rows [0,8192) and [8192,16384)).
// stats layout: [half][ {sum,sumsq} ][256]  -> half*512 + s*256 + col
// ---------------------------------------------------------------------------
__global__ __launch_bounds__(256) void bn_stats(const float* __restrict__ Y,
                                                float* __restrict__ stats)
{
    const int col = threadIdx.x;
    const int rb = blockIdx.x * 64;          // 64 rows per block; 8192%64==0
    const int half = (rb >= BATCH) ? 1 : 0;
    const float* p = Y + (size_t)rb * DH + col;
    float s = 0.f, q = 0.f;
#pragma unroll 8
    for (int r = 0; r < 64; ++r) {
        float v = p[(size_t)r * DH];
        s += v;
        q = fmaf(v, v, q);
    }
    atomicAdd(&stats[half * 512 + col], s);
    atomicAdd(&stats[half * 512 + 256 + col], q);
}

// ---------------------------------------------------------------------------
// In-place BN apply + ReLU: y = relu((y-mu)*rsqrt(var+eps)*g + beta)
// ---------------------------------------------------------------------------
__global__ __launch_bounds__(256) void bn_relu(float* __restrict__ Y,
                                               const float* __restrict__ stats,
                                               const float* __restrict__ g,
                                               const float* __restrict__ beta)
{
    const float invN = 1.0f / (float)BATCH;
    int idx = blockIdx.x * 256 + threadIdx.x;      // f4 index base; grid 1024
#pragma unroll
    for (int it = 0; it < 4; ++it) {
        int f = idx + it * (1024 * 256);           // 1,048,576 f4 total
        int row = f >> 6;                          // 64 f4 per row of 256
        int c0 = (f & 63) << 2;
        int half = (row >= BATCH) ? 1 : 0;
        f4 v = ((f4*)Y)[f];
#pragma unroll
        for (int j = 0; j < 4; ++j) {
            int c = c0 + j;
            float sum = stats[half * 512 + c];
            float sq  = stats[half * 512 + 256 + c];
            float mu = sum * invN;
            float var = fmaf(-mu, mu, sq * invN);
            float sc = g[c] * rsqrtf(var + EPS_BN);
            float sh = fmaf(-mu, sc, beta[c]);
            v[j] = fmaxf(fmaf(v[j], sc, sh), 0.f);
        }
        ((f4*)Y)[f] = v;
    }
}

// ---------------------------------------------------------------------------
// Row-normalize Z (16384 x 128) -> reps; accumulate S = sum of all reps rows.
// 64-lane group per row, 4 groups/block, 64 rows/block, grid 256.
// ---------------------------------------------------------------------------
__global__ __launch_bounds__(256) void rownorm_S(const float* __restrict__ Z,
                                                 float* __restrict__ reps,
                                                 float* __restrict__ Svec)
{
    const int lane = threadIdx.x & 63;
    const int grp = threadIdx.x >> 6;
    __shared__ float sS[DOUT];
    float s0 = 0.f, s1 = 0.f;
#pragma unroll 1
    for (int it = 0; it < 16; ++it) {
        int r = blockIdx.x * 64 + it * 4 + grp;
        float2 v = ((const float2*)(Z + (size_t)r * DOUT))[lane];
        float ss = fmaf(v.x, v.x, v.y * v.y);
#pragma unroll
        for (int o = 32; o; o >>= 1) ss += __shfl_xor(ss, o);
        float inv = 1.0f / fmaxf(sqrtf(ss), 1e-12f);
        float2 rv = make_float2(v.x * inv, v.y * inv);
        ((float2*)(reps + (size_t)r * DOUT))[lane] = rv;
        s0 += rv.x; s1 += rv.y;
    }
    if (threadIdx.x < DOUT) sS[threadIdx.x] = 0.f;
    __syncthreads();
    atomicAdd(&sS[lane * 2], s0);
    atomicAdd(&sS[lane * 2 + 1], s1);
    __syncthreads();
    if (threadIdx.x < DOUT) atomicAdd(&Svec[threadIdx.x], sS[threadIdx.x]);
}

// ---------------------------------------------------------------------------
// positives: pos[i] = reps_i . reps_{i+B}, one 64-lane group per pair
// ---------------------------------------------------------------------------
__global__ __launch_bounds__(256) void pos_kernel(const float* __restrict__ reps,
                                                  float* __restrict__ pos)
{
    const int lane = threadIdx.x & 63;
    const int grp = threadIdx.x >> 6;
    int p = blockIdx.x * 4 + grp;            // [0, 8192)
    float2 a = ((const float2*)(reps + (size_t)p * DOUT))[lane];
    float2 b = ((const float2*)(reps + (size_t)(p + BATCH) * DOUT))[lane];
    float d = fmaf(a.x, b.x, a.y * b.y);
#pragma unroll
    for (int o = 32; o; o >>= 1) d += __shfl_xor(d, o);
    if (lane == 0) pos[p] = d;
}

// ---------------------------------------------------------------------------
// loss: per row r: denom=(reps_r.S - reps_r.reps_r)/T; nom=exp(pos/T);
//       loss_r=-log(nom/denom); out = mean. 64 blocks, 256 rows each.
// ---------------------------------------------------------------------------
__global__ __launch_bounds__(256) void loss_kernel(const float* __restrict__ reps,
                                                   const float* __restrict__ Svec,
                                                   const float* __restrict__ pos,
                                                   float* __restrict__ out)
{
    const int lane = threadIdx.x & 63;
    const int grp = threadIdx.x >> 6;
    __shared__ float part[4];
    float2 sv = ((const float2*)Svec)[lane];
    float acc = 0.f;
#pragma unroll 1
    for (int it = 0; it < 64; ++it) {
        int r = blockIdx.x * 256 + it * 4 + grp;
        float2 v = ((const float2*)(reps + (size_t)r * DOUT))[lane];
        float rs = fmaf(v.x, sv.x, v.y * sv.y);   // reps_r . S  (partial)
        float sd = fmaf(v.x, v.x, v.y * v.y);     // reps_r . reps_r (partial)
#pragma unroll
        for (int o = 32; o; o >>= 1) {
            rs += __shfl_xor(rs, o);
            sd += __shfl_xor(sd, o);
        }
        if (lane == 0) {
            float p = pos[(r < BATCH) ? r : (r - BATCH)];
            float denom = (rs - sd) / TEMP;
            float nom = expf(p / TEMP);
            acc += -logf(nom / denom);
        }
    }
    if (lane == 0) part[grp] = acc;
    __syncthreads();
    if (threadIdx.x == 0) {
        float t = part[0] + part[1] + part[2] + part[3];
        atomicAdd(out, t * (1.0f / (float)MROWS));
    }
}

// zero the accumulator buffers (stats1, stats2, Svec) and the output scalar
__global__ void zero_kernel(float* __restrict__ smalls, float* __restrict__ out)
{
    int i = blockIdx.x * 256 + threadIdx.x;
    if (i < 2176) smalls[i] = 0.f;
    if (i == 0) out[0] = 0.f;
}

extern "C" void kernel_launch(void* const* d_in, const int* in_sizes, int n_in,
                              void* d_out, int out_size, void* d_ws, size_t ws_size,
                              hipStream_t stream)
{
    const float* x1    = (const float*)d_in[0];
    const float* x2    = (const float*)d_in[1];
    const float* W1    = (const float*)d_in[2];
    const float* b1    = (const float*)d_in[3];
    const float* g1    = (const float*)d_in[4];
    const float* beta1 = (const float*)d_in[5];
    const float* W2    = (const float*)d_in[6];
    const float* b2    = (const float*)d_in[7];
    const float* g2    = (const float*)d_in[8];
    const float* beta2 = (const float*)d_in[9];
    const float* W3    = (const float*)d_in[10];
    const float* b3    = (const float*)d_in[11];
    float* out = (float*)d_out;

    // workspace layout (floats):
    //   bufA: 4M (Y1/H1; later Z = bufA[0:2M), reps = bufA[2M:4M))
    //   bufB: 4M (Y2/H2)
    //   smalls @ 8M: stats1[1024], stats2[1024], Svec[128], pad, pos[8192]
    float* ws = (float*)d_ws;
    float* bufA = ws;
    float* bufB = ws + (1u << 22);
    float* Z    = bufA;
    float* reps = bufA + (1u << 21);
    float* smalls = ws + (1u << 23);
    float* stats1 = smalls;
    float* stats2 = smalls + 1024;
    float* Svec   = smalls + 2048;
    float* pos    = smalls + 2304;

    const int big = 1 << 30;   // splitRow sentinel: single-source GEMMs

    zero_kernel<<<9, 256, 0, stream>>>(smalls, out);

    // layer 1: [x1;x2] @ W1 + b1  (16384x512 @ 512x256)
    gemm_bias<128, 128, 8, DIN, DH, DIN / 32>
        <<<dim3(DH / 128, MROWS / 128), 256, 0, stream>>>(x1, x2, BATCH, W1, b1, bufA);
    bn_stats<<<MROWS / 64, 256, 0, stream>>>(bufA, stats1);
    bn_relu<<<1024, 256, 0, stream>>>(bufA, stats1, g1, beta1);

    // layer 2: H1 @ W2 + b2  (16384x256 @ 256x256)
    gemm_bias<128, 128, 8, DH, DH, DH / 32>
        <<<dim3(DH / 128, MROWS / 128), 256, 0, stream>>>(bufA, bufA, big, W2, b2, bufB);
    bn_stats<<<MROWS / 64, 256, 0, stream>>>(bufB, stats2);
    bn_relu<<<1024, 256, 0, stream>>>(bufB, stats2, g2, beta2);

    // layer 3: H2 @ W3 + b3  (16384x256 @ 256x128) -> Z (into bufA, H1 is dead)
    gemm_bias<128, 64, 4, DH, DOUT, DH / 32>
        <<<dim3(DOUT / 64, MROWS / 128), 256, 0, stream>>>(bufB, bufB, big, W3, b3, Z);

    // normalize rows, accumulate S, positives, loss
    rownorm_S<<<MROWS / 64, 256, 0, stream>>>(Z, reps, Svec);
    pos_kernel<<<BATCH / 4, 256, 0, stream>>>(reps, pos);
    loss_kernel<<<64, 256, 0, stream>>>(reps, Svec, pos, out);
}

// Round 2
// 322.730 us; speedup vs baseline: 2.0778x; 2.0778x over previous
//
#include <hip/hip_runtime.h>
#include <math.h>

// Problem constants (from reference)
#define BATCH   8192
#define MROWS   16384      // 2*BATCH rows processed through the MLP
#define DIN     512
#define DH      256
#define DOUT    128
#define EPS_BN  1e-5f
#define TEMP    0.07f

using f4 = __attribute__((ext_vector_type(4))) float;

// async global->LDS, 16B per lane, wave-uniform LDS base + lane*16 (m97 pattern)
#define GLD_LDS16(gp, lp) __builtin_amdgcn_global_load_lds( \
    (const __attribute__((address_space(1))) void*)(gp),    \
    (__attribute__((address_space(3))) void*)(lp), 16, 0, 0)

// ---------------------------------------------------------------------------
// fp32 GEMM + bias, C[M x N] = A[M x K] @ W[K x N] + bias.
// Round-2 rewrite: the round-1 version spilled acc to scratch every k-tile
// (WRITE_SIZE 516 MB vs 17 MB ideal -> 320us). Changes:
//   - B staged via async global_load_lds into linear LDS (0 VGPRs held)
//   - A reg-staged (16 VGPRs) with XOR-swizzled transpose store (2-way, free)
//   - LDS double-buffer, ONE barrier per k-tile
//   - k-loop unroll 8 (not 32) to keep scheduler live-ranges small
// ---------------------------------------------------------------------------
template <int BM, int BN, int TN, int K, int N, int NT>
__global__ __launch_bounds__(256, 2) void gemm_bias(
    const float* __restrict__ A1, const float* __restrict__ A2, int splitRow,
    const float* __restrict__ Wm, const float* __restrict__ bias,
    float* __restrict__ C)
{
    constexpr int BK = 32;
    constexpr int AF4 = BM * BK / (4 * 256);   // float4 A loads per thread (4)

    const int tid = threadIdx.x;
    const int tx = tid & 15;
    const int ty = tid >> 4;
    const int wave = tid >> 6;
    const int lane = tid & 63;
    const int brow = blockIdx.y * BM;
    const int bcol = blockIdx.x * BN;

    __shared__ float As[2][BK][BM];   // [k][row] transposed, XOR-swizzled cols
    __shared__ float Bs[2][BK][BN];   // [k][col] linear (global_load_lds dest)

    f4 ra[AF4];

    auto loadA = [&](int t) {
#pragma unroll
        for (int i = 0; i < AF4; ++i) {
            int l = i * 256 + tid;          // float4 index in BM x BK tile
            int row = l >> 3;               // 8 float4 per row (BK=32)
            int kq = (l & 7) << 2;
            int gr = brow + row;
            const float* src = (gr < splitRow) ? (A1 + (size_t)gr * K)
                                               : (A2 + (size_t)(gr - splitRow) * K);
            ra[i] = *(const f4*)(src + t * BK + kq);
        }
    };
    auto storeA = [&](int buf) {
#pragma unroll
        for (int i = 0; i < AF4; ++i) {
            int l = i * 256 + tid;
            int row = l >> 3;
            int kq = (l & 7) << 2;
#pragma unroll
            for (int j = 0; j < 4; ++j) {
                int kk = kq + j;
                int sw = ((kk >> 1) & 7) << 2;      // bank-spread swizzle
                As[buf][kk][row ^ sw] = ra[i][j];
            }
        }
    };
    auto stageB = [&](int buf, int t) {
        constexpr int NCH = BK * BN / 256;   // 1024-B chunks in the B tile
        constexpr int RPC = 256 / BN;        // tile rows per chunk
        int f = lane << 2;                   // float idx within chunk
        int rr = f / BN;
        int cc = f % BN;
#pragma unroll
        for (int ch = wave; ch < NCH; ch += 4) {
            int r = ch * RPC + rr;
            const float* gp = Wm + (size_t)(t * BK + r) * N + bcol + cc;
            GLD_LDS16(gp, &Bs[buf][ch * RPC][0]);   // uniform base per wave
        }
    };

    float acc[8][TN] = {};

    // prologue: stage tile 0 into buffer 0
    stageB(0, 0);
    loadA(0);
    storeA(0);
    __syncthreads();                        // drains vmcnt (incl. async B)

    for (int t = 0; t < NT; ++t) {
        const int cur = t & 1, nxt = cur ^ 1;
        const bool more = (t + 1 < NT);
        if (more) {
            stageB(nxt, t + 1);             // async, in flight across compute
            loadA(t + 1);                   // 16 VGPRs held across compute
        }
        const float(*Asc)[BM] = As[cur];
        const float(*Bsc)[BN] = Bs[cur];
#pragma unroll 8
        for (int k = 0; k < BK; ++k) {
            int sw = ((k >> 1) & 7) << 2;
            f4 a0 = *(const f4*)&Asc[k][(ty * 4) ^ sw];
            f4 a1 = *(const f4*)&Asc[k][(ty * 4 + BM / 2) ^ sw];
            f4 b0 = *(const f4*)&Bsc[k][tx * 4];
            f4 b1;
            if constexpr (TN == 8) b1 = *(const f4*)&Bsc[k][tx * 4 + BN / 2];
#pragma unroll
            for (int j = 0; j < 4; ++j) {
#pragma unroll
                for (int c = 0; c < 4; ++c) {
                    acc[j][c]     = fmaf(a0[j], b0[c], acc[j][c]);
                    acc[4 + j][c] = fmaf(a1[j], b0[c], acc[4 + j][c]);
                    if constexpr (TN == 8) {
                        acc[j][4 + c]     = fmaf(a0[j], b1[c], acc[j][4 + c]);
                        acc[4 + j][4 + c] = fmaf(a1[j], b1[c], acc[4 + j][4 + c]);
                    }
                }
            }
        }
        if (more) storeA(nxt);              // vmcnt wait on ra handled by compiler
        __syncthreads();                    // [nxt] full, [cur] reusable
    }

    // epilogue: + bias, coalesced float4 stores
    f4 b0v = *(const f4*)(bias + bcol + tx * 4);
    f4 b1v;
    if constexpr (TN == 8) b1v = *(const f4*)(bias + bcol + BN / 2 + tx * 4);
#pragma unroll
    for (int q = 0; q < 2; ++q) {
#pragma unroll
        for (int j = 0; j < 4; ++j) {
            int gr = brow + q * (BM / 2) + ty * 4 + j;
            f4 v, w;
#pragma unroll
            for (int c = 0; c < 4; ++c) v[c] = acc[q * 4 + j][c] + b0v[c];
            *(f4*)(C + (size_t)gr * N + bcol + tx * 4) = v;
            if constexpr (TN == 8) {
#pragma unroll
                for (int c = 0; c < 4; ++c) w[c] = acc[q * 4 + j][4 + c] + b1v[c];
                *(f4*)(C + (size_t)gr * N + bcol + BN / 2 + tx * 4) = w;
            }
        }
    }
}

// ---------------------------------------------------------------------------
// BN column stats (sum, sumsq) per half (rows [0,8192) and [8192,16384)).
// stats layout: [half][ {sum,sumsq} ][256]  -> half*512 + s*256 + col
// ---------------------------------------------------------------------------
__global__ __launch_bounds__(256) void bn_stats(const float* __restrict__ Y,
                                                float* __restrict__ stats)
{
    const int col = threadIdx.x;
    const int rb = blockIdx.x * 64;          // 64 rows per block; 8192%64==0
    const int half = (rb >= BATCH) ? 1 : 0;
    const float* p = Y + (size_t)rb * DH + col;
    float s = 0.f, q = 0.f;
#pragma unroll 8
    for (int r = 0; r < 64; ++r) {
        float v = p[(size_t)r * DH];
        s += v;
        q = fmaf(v, v, q);
    }
    atomicAdd(&stats[half * 512 + col], s);
    atomicAdd(&stats[half * 512 + 256 + col], q);
}

// ---------------------------------------------------------------------------
// In-place BN apply + ReLU: y = relu((y-mu)*rsqrt(var+eps)*g + beta)
// ---------------------------------------------------------------------------
__global__ __launch_bounds__(256) void bn_relu(float* __restrict__ Y,
                                               const float* __restrict__ stats,
                                               const float* __restrict__ g,
                                               const float* __restrict__ beta)
{
    const float invN = 1.0f / (float)BATCH;
    int idx = blockIdx.x * 256 + threadIdx.x;      // f4 index base; grid 1024
#pragma unroll
    for (int it = 0; it < 4; ++it) {
        int f = idx + it * (1024 * 256);           // 1,048,576 f4 total
        int row = f >> 6;                          // 64 f4 per row of 256
        int c0 = (f & 63) << 2;
        int half = (row >= BATCH) ? 1 : 0;
        f4 v = ((f4*)Y)[f];
#pragma unroll
        for (int j = 0; j < 4; ++j) {
            int c = c0 + j;
            float sum = stats[half * 512 + c];
            float sq  = stats[half * 512 + 256 + c];
            float mu = sum * invN;
            float var = fmaf(-mu, mu, sq * invN);
            float sc = g[c] * rsqrtf(var + EPS_BN);
            float sh = fmaf(-mu, sc, beta[c]);
            v[j] = fmaxf(fmaf(v[j], sc, sh), 0.f);
        }
        ((f4*)Y)[f] = v;
    }
}

// ---------------------------------------------------------------------------
// Row-normalize Z (16384 x 128) -> reps; accumulate S = sum of all reps rows.
// ---------------------------------------------------------------------------
__global__ __launch_bounds__(256) void rownorm_S(const float* __restrict__ Z,
                                                 float* __restrict__ reps,
                                                 float* __restrict__ Svec)
{
    const int lane = threadIdx.x & 63;
    const int grp = threadIdx.x >> 6;
    __shared__ float sS[DOUT];
    float s0 = 0.f, s1 = 0.f;
#pragma unroll 1
    for (int it = 0; it < 16; ++it) {
        int r = blockIdx.x * 64 + it * 4 + grp;
        float2 v = ((const float2*)(Z + (size_t)r * DOUT))[lane];
        float ss = fmaf(v.x, v.x, v.y * v.y);
#pragma unroll
        for (int o = 32; o; o >>= 1) ss += __shfl_xor(ss, o);
        float inv = 1.0f / fmaxf(sqrtf(ss), 1e-12f);
        float2 rv = make_float2(v.x * inv, v.y * inv);
        ((float2*)(reps + (size_t)r * DOUT))[lane] = rv;
        s0 += rv.x; s1 += rv.y;
    }
    if (threadIdx.x < DOUT) sS[threadIdx.x] = 0.f;
    __syncthreads();
    atomicAdd(&sS[lane * 2], s0);
    atomicAdd(&sS[lane * 2 + 1], s1);
    __syncthreads();
    if (threadIdx.x < DOUT) atomicAdd(&Svec[threadIdx.x], sS[threadIdx.x]);
}

// ---------------------------------------------------------------------------
// positives: pos[i] = reps_i . reps_{i+B}, one 64-lane group per pair
// ---------------------------------------------------------------------------
__global__ __launch_bounds__(256) void pos_kernel(const float* __restrict__ reps,
                                                  float* __restrict__ pos)
{
    const int lane = threadIdx.x & 63;
    const int grp = threadIdx.x >> 6;
    int p = blockIdx.x * 4 + grp;            // [0, 8192)
    float2 a = ((const float2*)(reps + (size_t)p * DOUT))[lane];
    float2 b = ((const float2*)(reps + (size_t)(p + BATCH) * DOUT))[lane];
    float d = fmaf(a.x, b.x, a.y * b.y);
#pragma unroll
    for (int o = 32; o; o >>= 1) d += __shfl_xor(d, o);
    if (lane == 0) pos[p] = d;
}

// ---------------------------------------------------------------------------
// loss: per row r: denom=(reps_r.S - reps_r.reps_r)/T; nom=exp(pos/T);
//       loss_r=-log(nom/denom); out = mean.
// ---------------------------------------------------------------------------
__global__ __launch_bounds__(256) void loss_kernel(const float* __restrict__ reps,
                                                   const float* __restrict__ Svec,
                                                   const float* __restrict__ pos,
                                                   float* __restrict__ out)
{
    const int lane = threadIdx.x & 63;
    const int grp = threadIdx.x >> 6;
    __shared__ float part[4];
    float2 sv = ((const float2*)Svec)[lane];
    float acc = 0.f;
#pragma unroll 1
    for (int it = 0; it < 64; ++it) {
        int r = blockIdx.x * 256 + it * 4 + grp;
        float2 v = ((const float2*)(reps + (size_t)r * DOUT))[lane];
        float rs = fmaf(v.x, sv.x, v.y * sv.y);   // reps_r . S  (partial)
        float sd = fmaf(v.x, v.x, v.y * v.y);     // reps_r . reps_r (partial)
#pragma unroll
        for (int o = 32; o; o >>= 1) {
            rs += __shfl_xor(rs, o);
            sd += __shfl_xor(sd, o);
        }
        if (lane == 0) {
            float p = pos[(r < BATCH) ? r : (r - BATCH)];
            float denom = (rs - sd) / TEMP;
            float nom = expf(p / TEMP);
            acc += -logf(nom / denom);
        }
    }
    if (lane == 0) part[grp] = acc;
    __syncthreads();
    if (threadIdx.x == 0) {
        float t = part[0] + part[1] + part[2] + part[3];
        atomicAdd(out, t * (1.0f / (float)MROWS));
    }
}

// zero the accumulator buffers (stats1, stats2, Svec) and the output scalar
__global__ void zero_kernel(float* __restrict__ smalls, float* __restrict__ out)
{
    int i = blockIdx.x * 256 + threadIdx.x;
    if (i < 2176) smalls[i] = 0.f;
    if (i == 0) out[0] = 0.f;
}

extern "C" void kernel_launch(void* const* d_in, const int* in_sizes, int n_in,
                              void* d_out, int out_size, void* d_ws, size_t ws_size,
                              hipStream_t stream)
{
    const float* x1    = (const float*)d_in[0];
    const float* x2    = (const float*)d_in[1];
    const float* W1    = (const float*)d_in[2];
    const float* b1    = (const float*)d_in[3];
    const float* g1    = (const float*)d_in[4];
    const float* beta1 = (const float*)d_in[5];
    const float* W2    = (const float*)d_in[6];
    const float* b2    = (const float*)d_in[7];
    const float* g2    = (const float*)d_in[8];
    const float* beta2 = (const float*)d_in[9];
    const float* W3    = (const float*)d_in[10];
    const float* b3    = (const float*)d_in[11];
    float* out = (float*)d_out;

    // workspace layout (floats):
    //   bufA: 4M (Y1/H1; later Z = bufA[0:2M), reps = bufA[2M:4M))
    //   bufB: 4M (Y2/H2)
    //   smalls @ 8M: stats1[1024], stats2[1024], Svec[128], pad, pos[8192]
    float* ws = (float*)d_ws;
    float* bufA = ws;
    float* bufB = ws + (1u << 22);
    float* Z    = bufA;
    float* reps = bufA + (1u << 21);
    float* smalls = ws + (1u << 23);
    float* stats1 = smalls;
    float* stats2 = smalls + 1024;
    float* Svec   = smalls + 2048;
    float* pos    = smalls + 2304;

    const int big = 1 << 30;   // splitRow sentinel: single-source GEMMs

    zero_kernel<<<9, 256, 0, stream>>>(smalls, out);

    // layer 1: [x1;x2] @ W1 + b1  (16384x512 @ 512x256)
    gemm_bias<128, 128, 8, DIN, DH, DIN / 32>
        <<<dim3(DH / 128, MROWS / 128), 256, 0, stream>>>(x1, x2, BATCH, W1, b1, bufA);
    bn_stats<<<MROWS / 64, 256, 0, stream>>>(bufA, stats1);
    bn_relu<<<1024, 256, 0, stream>>>(bufA, stats1, g1, beta1);

    // layer 2: H1 @ W2 + b2  (16384x256 @ 256x256)
    gemm_bias<128, 128, 8, DH, DH, DH / 32>
        <<<dim3(DH / 128, MROWS / 128), 256, 0, stream>>>(bufA, bufA, big, W2, b2, bufB);
    bn_stats<<<MROWS / 64, 256, 0, stream>>>(bufB, stats2);
    bn_relu<<<1024, 256, 0, stream>>>(bufB, stats2, g2, beta2);

    // layer 3: H2 @ W3 + b3  (16384x256 @ 256x128) -> Z (into bufA, H1 is dead)
    gemm_bias<128, 64, 4, DH, DOUT, DH / 32>
        <<<dim3(DOUT / 64, MROWS / 128), 256, 0, stream>>>(bufB, bufB, big, W3, b3, Z);

    // normalize rows, accumulate S, positives, loss
    rownorm_S<<<MROWS / 64, 256, 0, stream>>>(Z, reps, Svec);
    pos_kernel<<<BATCH / 4, 256, 0, stream>>>(reps, pos);
    loss_kernel<<<64, 256, 0, stream>>>(reps, Svec, pos, out);
}

// Round 3
// 233.647 us; speedup vs baseline: 2.8700x; 1.3813x over previous
//
#include <hip/hip_runtime.h>
#include <math.h>

// Problem constants (from reference)
#define BATCH   8192
#define MROWS   16384      // 2*BATCH rows processed through the MLP
#define DIN     512
#define DH      256
#define DOUT    128
#define EPS_BN  1e-5f
#define TEMP    0.07f

using f4 = __attribute__((ext_vector_type(4))) float;

// async global->LDS, 16B per lane, wave-uniform LDS base + lane*16
#define GLD_LDS16(gp, lp) __builtin_amdgcn_global_load_lds( \
    (const __attribute__((address_space(1))) void*)(gp),    \
    (__attribute__((address_space(3))) void*)(lp), 16, 0, 0)

// ---------------------------------------------------------------------------
// Fused fp32 GEMM:  C[M x N] = A[M x K] @ W[K x N] + bias, plus epilogue:
//   EPI=0: write C and atomically accumulate per-column BN stats (sum, sumsq)
//          into red[half*512 + {0,256} + col]  (half = brow>=BATCH)
//   EPI=1: BN==N==DOUT: row-normalize in-block, write reps, accumulate Svec
// A consumed in natural [row][k] layout -> BOTH A and B staged via
// global_load_lds (no reg staging, no transpose stores, 1 barrier/k-tile).
// A k-groups are swizzled on the GLOBAL side (g ^= row&7) so the strided
// a-reads are 2-way conflict-free (LDS dest must stay linear: rule #21).
// Thread layout fixed 256 = (16 tx, 16 ty). TM=8 -> rows ty*4+j and +64;
// TN in {4,8} -> cols tx*4 (+64).
// ---------------------------------------------------------------------------
template <int BM, int BN, int TM, int TN, int K, int N, int NT, int EPI>
__global__ __launch_bounds__(256, 2) void gemm_fused(
    const float* __restrict__ A1, const float* __restrict__ A2, int splitRow,
    const float* __restrict__ Wm, const float* __restrict__ bias,
    float* __restrict__ Cout, float* __restrict__ red)
{
    constexpr int BK = 32;
    constexpr int MB = TM / 4;              // row quad-blocks (stride 64)
    constexpr int NB = TN / 4;              // col quad-blocks (stride 64)
    constexpr int NCHA = BM / 8;            // 1KB chunks in A tile (8 rows each)
    constexpr int NCHB = (BK * BN) / 256;   // 1KB chunks in B tile
    constexpr int RPC = 256 / BN;           // B rows per chunk
    constexpr int SP = (EPI == 0) ? 2 : 1;  // reduction planes (sum[,sumsq])

    const int tid = threadIdx.x;
    const int tx = tid & 15;
    const int ty = tid >> 4;
    const int wave = tid >> 6;
    const int lane = tid & 63;
    const int brow = blockIdx.y * BM;
    const int bcol = blockIdx.x * BN;

    __shared__ float As[2][BM][BK];
    __shared__ float Bs[2][BK][BN];
    __shared__ float sRed[SP][16][BN];

    const int arow = lane >> 3;             // row within 8-row A chunk
    const int akg  = (lane & 7) ^ arow;     // swizzled source k-group
    const int brr  = lane / (BN / 4);       // B row within chunk
    const int bcc  = (lane % (BN / 4)) * 4; // B col within chunk

    auto stage = [&](int buf, int t) {
#pragma unroll
        for (int i = 0; i < NCHA / 4; ++i) {
            int ch = i * 4 + wave;
            int gr = brow + ch * 8 + arow;
            const float* src = (gr < splitRow) ? (A1 + (size_t)gr * K)
                                               : (A2 + (size_t)(gr - splitRow) * K);
            GLD_LDS16(src + t * BK + akg * 4, &As[buf][ch * 8][0]);
        }
#pragma unroll
        for (int i = 0; i < NCHB / 4; ++i) {
            int ch = i * 4 + wave;
            int r = t * BK + ch * RPC + brr;
            GLD_LDS16(Wm + (size_t)r * N + bcol + bcc, &Bs[buf][ch * RPC][0]);
        }
    };

    float acc[TM][TN] = {};

    stage(0, 0);
    __syncthreads();                         // compiler drains vmcnt here

    for (int t = 0; t < NT; ++t) {
        const int cur = t & 1, nxt = cur ^ 1;
        if (t + 1 < NT) stage(nxt, t + 1);   // async, in flight across compute
#pragma unroll
        for (int kc = 0; kc < BK / 4; ++kc) {
            f4 av[MB][4];                    // per-row f4 along k
#pragma unroll
            for (int mb = 0; mb < MB; ++mb)
#pragma unroll
                for (int jj = 0; jj < 4; ++jj) {
                    int r = ty * 4 + jj + mb * 64;
                    av[mb][jj] = ((const f4*)&As[cur][r][0])[kc ^ (r & 7)];
                }
#pragma unroll
            for (int kk = 0; kk < 4; ++kk) {
                f4 bv[NB];
#pragma unroll
                for (int cb = 0; cb < NB; ++cb)
                    bv[cb] = ((const f4*)&Bs[cur][kc * 4 + kk][0])[tx + cb * 16];
#pragma unroll
                for (int mb = 0; mb < MB; ++mb)
#pragma unroll
                    for (int jj = 0; jj < 4; ++jj)
#pragma unroll
                        for (int cb = 0; cb < NB; ++cb)
#pragma unroll
                            for (int c = 0; c < 4; ++c)
                                acc[mb * 4 + jj][cb * 4 + c] =
                                    fmaf(av[mb][jj][kk], bv[cb][c],
                                         acc[mb * 4 + jj][cb * 4 + c]);
            }
        }
        __syncthreads();
    }

    f4 bias_v[NB];
#pragma unroll
    for (int cb = 0; cb < NB; ++cb)
        bias_v[cb] = *(const f4*)(bias + bcol + tx * 4 + cb * 64);

    if constexpr (EPI == 0) {
        // bias + store + BN column stats
        const int half = (brow >= BATCH) ? 1 : 0;
        float s[TN] = {}, q[TN] = {};
#pragma unroll
        for (int mb = 0; mb < MB; ++mb)
#pragma unroll
            for (int jj = 0; jj < 4; ++jj) {
                int gr = brow + ty * 4 + jj + mb * 64;
#pragma unroll
                for (int cb = 0; cb < NB; ++cb) {
                    f4 v;
#pragma unroll
                    for (int c = 0; c < 4; ++c) {
                        v[c] = acc[mb * 4 + jj][cb * 4 + c] + bias_v[cb][c];
                        s[cb * 4 + c] += v[c];
                        q[cb * 4 + c] = fmaf(v[c], v[c], q[cb * 4 + c]);
                    }
                    *(f4*)(Cout + (size_t)gr * N + bcol + tx * 4 + cb * 64) = v;
                }
            }
#pragma unroll
        for (int cb = 0; cb < NB; ++cb) {
            *(f4*)&sRed[0][ty][tx * 4 + cb * 64] = *(f4*)&s[cb * 4];
            *(f4*)&sRed[1][ty][tx * 4 + cb * 64] = *(f4*)&q[cb * 4];
        }
        __syncthreads();
        if (tid < BN) {
            float ss = 0.f, qq = 0.f;
#pragma unroll
            for (int i = 0; i < 16; ++i) { ss += sRed[0][i][tid]; qq += sRed[1][i][tid]; }
            atomicAdd(&red[half * 512 + bcol + tid], ss);
            atomicAdd(&red[half * 512 + 256 + bcol + tid], qq);
        }
    } else {
        // bias + row-normalize (block holds full rows) + reps + Svec partials
        float s[TN] = {};
#pragma unroll
        for (int jj = 0; jj < 4; ++jj) {     // MB==1 for EPI==1
            int gr = brow + ty * 4 + jj;
            f4 v[NB];
            float ssq = 0.f;
#pragma unroll
            for (int cb = 0; cb < NB; ++cb)
#pragma unroll
                for (int c = 0; c < 4; ++c) {
                    v[cb][c] = acc[jj][cb * 4 + c] + bias_v[cb][c];
                    ssq = fmaf(v[cb][c], v[cb][c], ssq);
                }
#pragma unroll
            for (int o = 1; o < 16; o <<= 1) ssq += __shfl_xor(ssq, o);
            float inv = 1.0f / fmaxf(sqrtf(ssq), 1e-12f);
#pragma unroll
            for (int cb = 0; cb < NB; ++cb) {
#pragma unroll
                for (int c = 0; c < 4; ++c) {
                    v[cb][c] *= inv;
                    s[cb * 4 + c] += v[cb][c];
                }
                *(f4*)(Cout + (size_t)gr * DOUT + tx * 4 + cb * 64) = v[cb];
            }
        }
#pragma unroll
        for (int cb = 0; cb < NB; ++cb)
            *(f4*)&sRed[0][ty][tx * 4 + cb * 64] = *(f4*)&s[cb * 4];
        __syncthreads();
        if (tid < BN) {
            float ss = 0.f;
#pragma unroll
            for (int i = 0; i < 16; ++i) ss += sRed[0][i][tid];
            atomicAdd(&red[tid], ss);
        }
    }
}

// ---------------------------------------------------------------------------
// In-place BN apply + ReLU. Block = 64 rows (half-uniform), thread owns a
// fixed f4 column -> scale/shift computed once, then 16 coalesced row-iters.
// ---------------------------------------------------------------------------
__global__ __launch_bounds__(256) void bn_relu(float* __restrict__ Y,
                                               const float* __restrict__ stats,
                                               const float* __restrict__ g,
                                               const float* __restrict__ beta)
{
    const int c0 = (threadIdx.x & 63) << 2;   // fixed f4 column
    const int rj = threadIdx.x >> 6;
    const int row0 = blockIdx.x * 64;
    const int half = (row0 >= BATCH) ? 1 : 0;
    const float invN = 1.0f / (float)BATCH;
    f4 sc, sh;
#pragma unroll
    for (int j = 0; j < 4; ++j) {
        int c = c0 + j;
        float mu = stats[half * 512 + c] * invN;
        float var = fmaf(-mu, mu, stats[half * 512 + 256 + c] * invN);
        float s = g[c] * rsqrtf(var + EPS_BN);
        sc[j] = s;
        sh[j] = fmaf(-mu, s, beta[c]);
    }
#pragma unroll 4
    for (int it = 0; it < 16; ++it) {
        int row = row0 + it * 4 + rj;
        f4 v = *(const f4*)(Y + (size_t)row * DH + c0);
#pragma unroll
        for (int j = 0; j < 4; ++j) v[j] = fmaxf(fmaf(v[j], sc[j], sh[j]), 0.f);
        *(f4*)(Y + (size_t)row * DH + c0) = v;
    }
}

// ---------------------------------------------------------------------------
// Fused positives + loss. Group of 64 lanes handles pair (i, i+B):
//   pos = reps_i . reps_{i+B};  per row r: denom=(reps_r.S - reps_r.reps_r)/T
//   loss_r = -log(exp(pos/T)/denom);  out = mean over 2B rows.
// ---------------------------------------------------------------------------
__global__ __launch_bounds__(256) void losspos(const float* __restrict__ reps,
                                               const float* __restrict__ Svec,
                                               float* __restrict__ out)
{
    const int lane = threadIdx.x & 63;
    const int grp = threadIdx.x >> 6;
    __shared__ float part[4];
    float2 sv = ((const float2*)Svec)[lane];
    float acc = 0.f;
#pragma unroll 1
    for (int it = 0; it < 8; ++it) {
        int p = blockIdx.x * 32 + it * 4 + grp;
        float2 a = ((const float2*)(reps + (size_t)p * DOUT))[lane];
        float2 b = ((const float2*)(reps + (size_t)(p + BATCH) * DOUT))[lane];
        float dp  = fmaf(a.x, b.x, a.y * b.y);
        float rsA = fmaf(a.x, sv.x, a.y * sv.y);
        float sdA = fmaf(a.x, a.x, a.y * a.y);
        float rsB = fmaf(b.x, sv.x, b.y * sv.y);
        float sdB = fmaf(b.x, b.x, b.y * b.y);
#pragma unroll
        for (int o = 32; o; o >>= 1) {
            dp  += __shfl_xor(dp, o);
            rsA += __shfl_xor(rsA, o);
            sdA += __shfl_xor(sdA, o);
            rsB += __shfl_xor(rsB, o);
            sdB += __shfl_xor(sdB, o);
        }
        if (lane == 0) {
            float nom = expf(dp / TEMP);
            float dA = (rsA - sdA) / TEMP;
            float dB = (rsB - sdB) / TEMP;
            acc += -logf(nom / dA) - logf(nom / dB);
        }
    }
    if (lane == 0) part[grp] = acc;
    __syncthreads();
    if (threadIdx.x == 0) {
        float t = part[0] + part[1] + part[2] + part[3];
        atomicAdd(out, t * (1.0f / (float)MROWS));
    }
}

// zero the accumulators (stats1, stats2, Svec) and the output scalar
__global__ void zero_kernel(float* __restrict__ smalls, float* __restrict__ out)
{
    int i = blockIdx.x * 256 + threadIdx.x;
    if (i < 2176) smalls[i] = 0.f;
    if (i == 0) out[0] = 0.f;
}

extern "C" void kernel_launch(void* const* d_in, const int* in_sizes, int n_in,
                              void* d_out, int out_size, void* d_ws, size_t ws_size,
                              hipStream_t stream)
{
    const float* x1    = (const float*)d_in[0];
    const float* x2    = (const float*)d_in[1];
    const float* W1    = (const float*)d_in[2];
    const float* b1    = (const float*)d_in[3];
    const float* g1    = (const float*)d_in[4];
    const float* beta1 = (const float*)d_in[5];
    const float* W2    = (const float*)d_in[6];
    const float* b2    = (const float*)d_in[7];
    const float* g2    = (const float*)d_in[8];
    const float* beta2 = (const float*)d_in[9];
    const float* W3    = (const float*)d_in[10];
    const float* b3    = (const float*)d_in[11];
    float* out = (float*)d_out;

    // workspace (floats): bufA 4M (Y1/H1, later reps), bufB 4M (Y2/H2),
    // smalls @ 8M: stats1[1024], stats2[1024], Svec[128]
    float* ws = (float*)d_ws;
    float* bufA = ws;
    float* bufB = ws + (1u << 22);
    float* reps = bufA;                 // H1 dead once G3 runs (reads bufB)
    float* smalls = ws + (1u << 23);
    float* stats1 = smalls;
    float* stats2 = smalls + 1024;
    float* Svec   = smalls + 2048;

    const int big = 1 << 30;            // splitRow sentinel: single-source GEMM

    zero_kernel<<<9, 256, 0, stream>>>(smalls, out);

    // L1: [x1;x2] @ W1 + b1 -> Y1 (+stats1).  grid 4x128 = 512 blocks
    gemm_fused<128, 64, 8, 4, DIN, DH, DIN / 32, 0>
        <<<dim3(DH / 64, MROWS / 128), 256, 0, stream>>>(x1, x2, BATCH, W1, b1,
                                                         bufA, stats1);
    bn_relu<<<MROWS / 64, 256, 0, stream>>>(bufA, stats1, g1, beta1);

    // L2: H1 @ W2 + b2 -> Y2 (+stats2).  grid 4x128 = 512 blocks
    gemm_fused<128, 64, 8, 4, DH, DH, DH / 32, 0>
        <<<dim3(DH / 64, MROWS / 128), 256, 0, stream>>>(bufA, bufA, big, W2, b2,
                                                         bufB, stats2);
    bn_relu<<<MROWS / 64, 256, 0, stream>>>(bufB, stats2, g2, beta2);

    // L3: H2 @ W3 + b3 -> row-normalized reps (+Svec).  grid 1x256
    gemm_fused<64, 128, 4, 8, DH, DOUT, DH / 32, 1>
        <<<dim3(DOUT / 128, MROWS / 64), 256, 0, stream>>>(bufB, bufB, big, W3, b3,
                                                           reps, Svec);

    // positives + loss (pair (i, i+B) per 64-lane group)
    losspos<<<BATCH / 32, 256, 0, stream>>>(reps, Svec, out);
}

// Round 4
// 220.486 us; speedup vs baseline: 3.0414x; 1.0597x over previous
//
#include <hip/hip_runtime.h>
#include <math.h>

// Problem constants (from reference)
#define BATCH   8192
#define MROWS   16384      // 2*BATCH rows processed through the MLP
#define DIN     512
#define DH      256
#define DOUT    128
#define EPS_BN  1e-5f
#define TEMP    0.07f

using f4   = __attribute__((ext_vector_type(4))) float;
using f32x4= __attribute__((ext_vector_type(4))) float;
using h4   = __attribute__((ext_vector_type(4))) _Float16;
using h8   = __attribute__((ext_vector_type(8))) _Float16;

// async global->LDS, 16B per lane: per-lane GLOBAL src, wave-uniform LDS base
#define GLD_LDS16(gp, lp) __builtin_amdgcn_global_load_lds( \
    (const __attribute__((address_space(1))) void*)(gp),    \
    (__attribute__((address_space(3))) void*)(lp), 16, 0, 0)

// ---------------------------------------------------------------------------
// fp16x3 GEMM on MFMA:  C = A@B + bias  with A,B split as hi+lo f16 and
//   A@B = Ahi@Bhi + Alo@Bhi + Ahi@Blo   (K' = 3K, phase p in {0,1,2})
// A: M x K row-major (hi/lo); BT: N x K row-major (= B^T, hi/lo).
// Tiles BM=64, BN=128, BK=64; 256 thr = 4 waves (2x2), wave-tile 32x64.
// mfma_f32_16x16x32_f16: A-frag lane l: row=l&15, k=(l>>4)*8+j (8 contig k)
//                        B-frag lane l: col=l&15, k=(l>>4)*8+j
//                        C   lane l: col=l&15, row=(l>>4)*4+reg   [m89]
// LDS is FRAGMENT-LINEAR (chunk = one 16x32 frag = 1KB, lane*16B inside),
// filled by global_load_lds with per-lane source addrs -> no ds_write at all,
// ds_read_b128 stride-1 conflict-free. 64B-contiguous global segments.
// EPI=0: store C + per-column BN stats (sum,sumsq) -> red[half*512+{0,256}+col]
// EPI=1: (N=128) row-normalize, store reps, accumulate Svec -> red[col]
// ---------------------------------------------------------------------------
template <int K, int N, int EPI>
__global__ __launch_bounds__(256, 2) void gemm3h(
    const _Float16* __restrict__ Ahi, const _Float16* __restrict__ Alo,
    const _Float16* __restrict__ BThi, const _Float16* __restrict__ BTlo,
    const float* __restrict__ bias, float* __restrict__ Cout,
    float* __restrict__ red)
{
    constexpr int BM = 64, BN = 128, BK = 64;
    constexpr int KT = K / BK;            // k-tiles per phase
    constexpr int NT = 3 * KT;

    const int tid = threadIdx.x;
    const int wave = tid >> 6, lane = tid & 63;
    const int wr = wave >> 1, wc = wave & 1;     // wave tile (32 x 64)
    const int l4 = lane >> 4, lc = lane & 15;
    const int brow = blockIdx.y * BM;
    const int bcol = blockIdx.x * BN;

    __shared__ _Float16 Alds[2][8 * 512];   // 8 chunks  (mf*2+ks), 16KB
    __shared__ _Float16 Blds[2][16 * 512];  // 16 chunks (nf*2+ks), 32KB
    __shared__ float sRed[2][8][BN];        // 8KB
    __shared__ float nLds[64][2];           // EPI==1 row-norm partials

    // staging: 24 chunks of 1KB; wave w takes A{2w,2w+1} + B{8+4w..8+4w+3}
    // chunk ch (A): row = 16*(ch>>1)+lc,  k-off = 32*(ch&1) + l4*8
    // chunk ch (B): same with BT rows (cols of B)
    size_t aRow[2], bRow[4];
    int aK[2], bK[4];
#pragma unroll
    for (int i = 0; i < 2; ++i) {
        int ch = 2 * wave + i;
        aRow[i] = (size_t)(brow + 16 * (ch >> 1) + lc) * K;
        aK[i] = 32 * (ch & 1) + l4 * 8;
    }
#pragma unroll
    for (int i = 0; i < 4; ++i) {
        int ch = 4 * wave + i;
        bRow[i] = (size_t)(bcol + 16 * (ch >> 1) + lc) * K;
        bK[i] = 32 * (ch & 1) + l4 * 8;
    }

    auto stage = [&](int buf, int t) {
        const int phase = t / KT;
        const int k0 = (t % KT) * BK;
        const _Float16* As = (phase == 1) ? Alo : Ahi;
        const _Float16* Bs = (phase == 2) ? BTlo : BThi;
#pragma unroll
        for (int i = 0; i < 2; ++i)
            GLD_LDS16(As + aRow[i] + k0 + aK[i], &Alds[buf][(2 * wave + i) * 512]);
#pragma unroll
        for (int i = 0; i < 4; ++i)
            GLD_LDS16(Bs + bRow[i] + k0 + bK[i], &Blds[buf][(4 * wave + i) * 512]);
    };

    f32x4 acc[2][4];
#pragma unroll
    for (int mi = 0; mi < 2; ++mi)
#pragma unroll
        for (int ni = 0; ni < 4; ++ni)
#pragma unroll
            for (int c = 0; c < 4; ++c) acc[mi][ni][c] = 0.f;

    stage(0, 0);
    __syncthreads();                          // drains vmcnt before first read

    for (int t = 0; t < NT; ++t) {
        const int cur = t & 1, nxt = cur ^ 1;
        if (t + 1 < NT) stage(nxt, t + 1);    // async, in flight over MFMAs
        h8 a[2][2], b[4][2];
#pragma unroll
        for (int mi = 0; mi < 2; ++mi)
#pragma unroll
            for (int ks = 0; ks < 2; ++ks)
                a[mi][ks] = *(const h8*)&Alds[cur][((wr * 2 + mi) * 2 + ks) * 512 + lane * 8];
#pragma unroll
        for (int ni = 0; ni < 4; ++ni)
#pragma unroll
            for (int ks = 0; ks < 2; ++ks)
                b[ni][ks] = *(const h8*)&Blds[cur][((wc * 4 + ni) * 2 + ks) * 512 + lane * 8];
#pragma unroll
        for (int ks = 0; ks < 2; ++ks)
#pragma unroll
            for (int mi = 0; mi < 2; ++mi)
#pragma unroll
                for (int ni = 0; ni < 4; ++ni)
                    acc[mi][ni] = __builtin_amdgcn_mfma_f32_16x16x32_f16(
                        a[mi][ks], b[ni][ks], acc[mi][ni], 0, 0, 0);
        __syncthreads();                      // [nxt] staged, [cur] reusable
    }

    float bv[4];
#pragma unroll
    for (int ni = 0; ni < 4; ++ni) bv[ni] = bias[bcol + wc * 64 + ni * 16 + lc];

    if constexpr (EPI == 0) {
        const int half = (brow >= BATCH) ? 1 : 0;
        float s[4] = {}, q[4] = {};
#pragma unroll
        for (int mi = 0; mi < 2; ++mi)
#pragma unroll
            for (int j = 0; j < 4; ++j) {
                int gr = brow + wr * 32 + mi * 16 + l4 * 4 + j;
#pragma unroll
                for (int ni = 0; ni < 4; ++ni) {
                    float v = acc[mi][ni][j] + bv[ni];
                    Cout[(size_t)gr * N + bcol + wc * 64 + ni * 16 + lc] = v;
                    s[ni] += v;
                    q[ni] = fmaf(v, v, q[ni]);
                }
            }
#pragma unroll
        for (int ni = 0; ni < 4; ++ni) {
            sRed[0][wr * 4 + l4][wc * 64 + ni * 16 + lc] = s[ni];
            sRed[1][wr * 4 + l4][wc * 64 + ni * 16 + lc] = q[ni];
        }
        __syncthreads();
        if (tid < BN) {
            float ss = 0.f, qq = 0.f;
#pragma unroll
            for (int i = 0; i < 8; ++i) { ss += sRed[0][i][tid]; qq += sRed[1][i][tid]; }
            atomicAdd(&red[half * 512 + bcol + tid], ss);
            atomicAdd(&red[half * 512 + 256 + bcol + tid], qq);
        }
    } else {
        // row-normalize: rows span (wc, ni, lc) -> shfl over lc + LDS over wc
        float v[2][4][4];                     // [mi][j][ni]
#pragma unroll
        for (int mi = 0; mi < 2; ++mi)
#pragma unroll
            for (int j = 0; j < 4; ++j) {
                float ssq = 0.f;
#pragma unroll
                for (int ni = 0; ni < 4; ++ni) {
                    v[mi][j][ni] = acc[mi][ni][j] + bv[ni];
                    ssq = fmaf(v[mi][j][ni], v[mi][j][ni], ssq);
                }
#pragma unroll
                for (int o = 1; o < 16; o <<= 1) ssq += __shfl_xor(ssq, o);
                if (lc == 0) nLds[wr * 32 + mi * 16 + l4 * 4 + j][wc] = ssq;
            }
        __syncthreads();
        float s[4] = {};
#pragma unroll
        for (int mi = 0; mi < 2; ++mi)
#pragma unroll
            for (int j = 0; j < 4; ++j) {
                int lrow = wr * 32 + mi * 16 + l4 * 4 + j;
                float tot = nLds[lrow][0] + nLds[lrow][1];
                float inv = 1.0f / fmaxf(sqrtf(tot), 1e-12f);
#pragma unroll
                for (int ni = 0; ni < 4; ++ni) {
                    float z = v[mi][j][ni] * inv;
                    Cout[(size_t)(brow + lrow) * DOUT + wc * 64 + ni * 16 + lc] = z;
                    s[ni] += z;
                }
            }
#pragma unroll
        for (int ni = 0; ni < 4; ++ni)
            sRed[0][wr * 4 + l4][wc * 64 + ni * 16 + lc] = s[ni];
        __syncthreads();
        if (tid < BN) {
            float ss = 0.f;
#pragma unroll
            for (int i = 0; i < 8; ++i) ss += sRed[0][i][tid];
            atomicAdd(&red[tid], ss);
        }
    }
}

// ---------------------------------------------------------------------------
// Prep: split [x1;x2] -> Xhi/Xlo (f16), and W1/W2/W3 -> transposed hi/lo f16.
// Blocks [0,2048): X (4096 elems each).  Blocks [2048,2272): W (1024 each).
// ---------------------------------------------------------------------------
__global__ __launch_bounds__(256) void split_xw(
    const float* __restrict__ x1, const float* __restrict__ x2,
    const float* __restrict__ W1, const float* __restrict__ W2,
    const float* __restrict__ W3,
    _Float16* __restrict__ Xhi, _Float16* __restrict__ Xlo,
    _Float16* __restrict__ W1hiT, _Float16* __restrict__ W1loT,
    _Float16* __restrict__ W2hiT, _Float16* __restrict__ W2loT,
    _Float16* __restrict__ W3hiT, _Float16* __restrict__ W3loT)
{
    const int b = blockIdx.x;
    if (b < 2048) {
        const float* src = (b < 1024) ? x1 : x2;
        const size_t goff = (b < 1024) ? 0 : (size_t)BATCH * DIN;
#pragma unroll
        for (int i = 0; i < 4; ++i) {
            size_t f = (size_t)(b & 1023) * 1024 + i * 256 + threadIdx.x;  // f4 idx
            f4 vv = ((const f4*)src)[f];
            h4 hi, lo;
#pragma unroll
            for (int j = 0; j < 4; ++j) {
                hi[j] = (_Float16)vv[j];
                lo[j] = (_Float16)(vv[j] - (float)hi[j]);
            }
            *(h4*)&Xhi[goff + f * 4] = hi;
            *(h4*)&Xlo[goff + f * 4] = lo;
        }
    } else {
        const int wb = b - 2048;
#pragma unroll
        for (int i = 0; i < 4; ++i) {
            int e = wb * 1024 + i * 256 + threadIdx.x;   // 0..229375
            float w;
            _Float16 hi;
            if (e < 131072) {                 // W1: K=512, N=256, out = [n][k]
                int n = e >> 9, k = e & 511;
                w = W1[(size_t)k * 256 + n];
                hi = (_Float16)w;
                W1hiT[e] = hi; W1loT[e] = (_Float16)(w - (float)hi);
            } else if (e < 196608) {          // W2: K=256, N=256
                int r = e - 131072;
                int n = r >> 8, k = r & 255;
                w = W2[(size_t)k * 256 + n];
                hi = (_Float16)w;
                W2hiT[r] = hi; W2loT[r] = (_Float16)(w - (float)hi);
            } else {                          // W3: K=256, N=128
                int r = e - 196608;
                int n = r >> 8, k = r & 255;
                w = W3[(size_t)k * 128 + n];
                hi = (_Float16)w;
                W3hiT[r] = hi; W3loT[r] = (_Float16)(w - (float)hi);
            }
        }
    }
}

// ---------------------------------------------------------------------------
// BN apply + ReLU + f16 hi/lo split:  H = relu(y*sc+sh) -> Hhi, Hlo
// Block = 64 rows; thread owns a fixed f4 column; 16 coalesced row-iters.
// ---------------------------------------------------------------------------
__global__ __launch_bounds__(256) void bnrelu_split(
    const float* __restrict__ Y, const float* __restrict__ stats,
    const float* __restrict__ g, const float* __restrict__ beta,
    _Float16* __restrict__ Hhi, _Float16* __restrict__ Hlo)
{
    const int c0 = (threadIdx.x & 63) << 2;
    const int rj = threadIdx.x >> 6;
    const int row0 = blockIdx.x * 64;
    const int half = (row0 >= BATCH) ? 1 : 0;
    const float invN = 1.0f / (float)BATCH;
    f4 sc, sh;
#pragma unroll
    for (int j = 0; j < 4; ++j) {
        int c = c0 + j;
        float mu = stats[half * 512 + c] * invN;
        float var = fmaf(-mu, mu, stats[half * 512 + 256 + c] * invN);
        float s = g[c] * rsqrtf(var + EPS_BN);
        sc[j] = s;
        sh[j] = fmaf(-mu, s, beta[c]);
    }
#pragma unroll 4
    for (int it = 0; it < 16; ++it) {
        int row = row0 + it * 4 + rj;
        f4 v = *(const f4*)(Y + (size_t)row * DH + c0);
        h4 hi, lo;
#pragma unroll
        for (int j = 0; j < 4; ++j) {
            float h = fmaxf(fmaf(v[j], sc[j], sh[j]), 0.f);
            hi[j] = (_Float16)h;
            lo[j] = (_Float16)(h - (float)hi[j]);
        }
        *(h4*)&Hhi[(size_t)row * DH + c0] = hi;
        *(h4*)&Hlo[(size_t)row * DH + c0] = lo;
    }
}

// ---------------------------------------------------------------------------
// Fused positives + loss. 64-lane group handles pair (i, i+B).
// ---------------------------------------------------------------------------
__global__ __launch_bounds__(256) void losspos(const float* __restrict__ reps,
                                               const float* __restrict__ Svec,
                                               float* __restrict__ out)
{
    const int lane = threadIdx.x & 63;
    const int grp = threadIdx.x >> 6;
    __shared__ float part[4];
    float2 sv = ((const float2*)Svec)[lane];
    float acc = 0.f;
#pragma unroll 1
    for (int it = 0; it < 8; ++it) {
        int p = blockIdx.x * 32 + it * 4 + grp;
        float2 a = ((const float2*)(reps + (size_t)p * DOUT))[lane];
        float2 b = ((const float2*)(reps + (size_t)(p + BATCH) * DOUT))[lane];
        float dp  = fmaf(a.x, b.x, a.y * b.y);
        float rsA = fmaf(a.x, sv.x, a.y * sv.y);
        float sdA = fmaf(a.x, a.x, a.y * a.y);
        float rsB = fmaf(b.x, sv.x, b.y * sv.y);
        float sdB = fmaf(b.x, b.x, b.y * b.y);
#pragma unroll
        for (int o = 32; o; o >>= 1) {
            dp  += __shfl_xor(dp, o);
            rsA += __shfl_xor(rsA, o);
            sdA += __shfl_xor(sdA, o);
            rsB += __shfl_xor(rsB, o);
            sdB += __shfl_xor(sdB, o);
        }
        if (lane == 0) {
            float nom = expf(dp / TEMP);
            float dA = (rsA - sdA) / TEMP;
            float dB = (rsB - sdB) / TEMP;
            acc += -logf(nom / dA) - logf(nom / dB);
        }
    }
    if (lane == 0) part[grp] = acc;
    __syncthreads();
    if (threadIdx.x == 0) {
        float t = part[0] + part[1] + part[2] + part[3];
        atomicAdd(out, t * (1.0f / (float)MROWS));
    }
}

// zero the accumulators (stats1, stats2, Svec) and the output scalar
__global__ void zero_kernel(float* __restrict__ smalls, float* __restrict__ out)
{
    int i = blockIdx.x * 256 + threadIdx.x;
    if (i < 2176) smalls[i] = 0.f;
    if (i == 0) out[0] = 0.f;
}

extern "C" void kernel_launch(void* const* d_in, const int* in_sizes, int n_in,
                              void* d_out, int out_size, void* d_ws, size_t ws_size,
                              hipStream_t stream)
{
    const float* x1    = (const float*)d_in[0];
    const float* x2    = (const float*)d_in[1];
    const float* W1    = (const float*)d_in[2];
    const float* b1    = (const float*)d_in[3];
    const float* g1    = (const float*)d_in[4];
    const float* beta1 = (const float*)d_in[5];
    const float* W2    = (const float*)d_in[6];
    const float* b2    = (const float*)d_in[7];
    const float* g2    = (const float*)d_in[8];
    const float* beta2 = (const float*)d_in[9];
    const float* W3    = (const float*)d_in[10];
    const float* b3    = (const float*)d_in[11];
    float* out = (float*)d_out;

    // workspace overlay (byte offsets), peak ~49.3MB:
    //  [0,16M):  Xhi (G1)      -> H1hi/H1lo (8M each, after G1)  -> H2hi/H2lo
    //  [16,32M): Xlo (G1)      -> Y2 (G2)   -> reps (G3)
    //  [32,48M): Y1 (G1 out)
    //  [48M,..): W splits (896KB) + stats1/stats2/Svec (8.7KB)
    char* W = (char*)d_ws;
    _Float16* XHI  = (_Float16*)(W);
    _Float16* XLO  = (_Float16*)(W + (16u << 20));
    float*    Y1   = (float*)   (W + (32u << 20));
    _Float16* H1HI = (_Float16*)(W);
    _Float16* H1LO = (_Float16*)(W + (8u << 20));
    float*    Y2   = (float*)   (W + (16u << 20));
    _Float16* H2HI = (_Float16*)(W);
    _Float16* H2LO = (_Float16*)(W + (8u << 20));
    float*    REPS = (float*)   (W + (16u << 20));
    char* wb = W + (48u << 20);
    _Float16* W1HIT = (_Float16*)(wb);
    _Float16* W1LOT = (_Float16*)(wb + 262144);
    _Float16* W2HIT = (_Float16*)(wb + 524288);
    _Float16* W2LOT = (_Float16*)(wb + 655360);
    _Float16* W3HIT = (_Float16*)(wb + 786432);
    _Float16* W3LOT = (_Float16*)(wb + 851968);
    float* smalls   = (float*)  (wb + 917504);
    float* stats1 = smalls;
    float* stats2 = smalls + 1024;
    float* Svec   = smalls + 2048;

    zero_kernel<<<9, 256, 0, stream>>>(smalls, out);

    // prep: X hi/lo split + W transposed hi/lo splits
    split_xw<<<2272, 256, 0, stream>>>(x1, x2, W1, W2, W3, XHI, XLO,
                                       W1HIT, W1LOT, W2HIT, W2LOT, W3HIT, W3LOT);

    // L1: X @ W1 + b1 -> Y1 (+stats1).  grid 2x256 = 512 blocks
    gemm3h<DIN, DH, 0><<<dim3(DH / 128, MROWS / 64), 256, 0, stream>>>(
        XHI, XLO, W1HIT, W1LOT, b1, Y1, stats1);
    bnrelu_split<<<MROWS / 64, 256, 0, stream>>>(Y1, stats1, g1, beta1, H1HI, H1LO);

    // L2: H1 @ W2 + b2 -> Y2 (+stats2)
    gemm3h<DH, DH, 0><<<dim3(DH / 128, MROWS / 64), 256, 0, stream>>>(
        H1HI, H1LO, W2HIT, W2LOT, b2, Y2, stats2);
    bnrelu_split<<<MROWS / 64, 256, 0, stream>>>(Y2, stats2, g2, beta2, H2HI, H2LO);

    // L3: H2 @ W3 + b3 -> row-normalized reps (+Svec)
    gemm3h<DH, DOUT, 1><<<dim3(DOUT / 128, MROWS / 64), 256, 0, stream>>>(
        H2HI, H2LO, W3HIT, W3LOT, b3, REPS, Svec);

    // positives + loss
    losspos<<<BATCH / 32, 256, 0, stream>>>(REPS, Svec, out);
}

// Round 5
// 190.552 us; speedup vs baseline: 3.5191x; 1.1571x over previous
//
#include <hip/hip_runtime.h>
#include <math.h>

// Problem constants (from reference)
#define BATCH   8192
#define MROWS   16384      // 2*BATCH rows processed through the MLP
#define DIN     512
#define DH      256
#define DOUT    128
#define EPS_BN  1e-5f
#define TEMP    0.07f

using f4    = __attribute__((ext_vector_type(4))) float;
using f32x4 = __attribute__((ext_vector_type(4))) float;
using h4    = __attribute__((ext_vector_type(4))) _Float16;
using h8    = __attribute__((ext_vector_type(8))) _Float16;

// async global->LDS, 16B per lane: per-lane GLOBAL src, wave-uniform LDS base
#define GLD_LDS16(gp, lp) __builtin_amdgcn_global_load_lds( \
    (const __attribute__((address_space(1))) void*)(gp),    \
    (__attribute__((address_space(3))) void*)(lp), 16, 0, 0)

// ---------------------------------------------------------------------------
// Tiled ("chunk-linear") operand layout shared by all GEMM operands:
//   tile = 64 rows x 64 k (A) or 128 cols x 64 k (B^T), chunk = 1KB:
//   A: tileIdx = (r/64)*(K/64)+(k/64), ch=((r%64)/16)*2+((k%64)/32),
//      lane=(r%16)+(((k%32)/8)*16), off=k%8
//      halfIdx = tileIdx*4096 + ch*512 + lane*8 + off
//   B^T: same with cols: tileIdx=(n/128)*(K/64)+(k/64), ch=((n%128)/16)*2+...,
//      halfIdx = tileIdx*8192 + ch*512 + lane*8 + off
// So one global_load_lds = 1KB CONTIGUOUS, and LDS ends up fragment-linear
// for mfma_f32_16x16x32_f16 (same frag mapping as round 4, which passed).
// ---------------------------------------------------------------------------

// ---------------------------------------------------------------------------
// fp16x3 GEMM, phases fused per k-tile:
//   acc += Ahi.Bhi + Alo.Bhi + Ahi.Blo  (48 MFMA / tile)
// Ring-3 LDS (3 x 48KB), counted vmcnt(12) + raw s_barrier, 1 barrier/tile.
// Per tile each wave stages 12 x 1KB chunks (A-hi 8, A-lo 8, B-hi 16, B-lo 16
// split across 4 waves).  Safety: stage(t+2) issued after top-of-t barrier =>
// every wave has finished reading ring[(t+2)%3] (last read at tile t-1).
// EPI=0: store C + BN column stats; EPI=1: row-normalize + reps + Svec.
// ---------------------------------------------------------------------------
template <int K, int N, int EPI>
__global__ __launch_bounds__(256, 1) void gemm3h(
    const _Float16* __restrict__ Ahi, const _Float16* __restrict__ Alo,
    const _Float16* __restrict__ BThi, const _Float16* __restrict__ BTlo,
    const float* __restrict__ bias, float* __restrict__ Cout,
    float* __restrict__ red)
{
    constexpr int BM = 64, BN = 128;
    constexpr int NT = K / 64;              // fused k-tiles
    constexpr int TA = 4096, TB = 8192;     // halfs per A/B tile
    constexpr int BUF = 24576;              // halfs per ring buffer (48KB)

    __shared__ _Float16 ring[3][BUF];       // 144KB; epilogue aliases buf 0

    const int tid = threadIdx.x;
    const int wave = tid >> 6, lane = tid & 63;
    const int wr = wave >> 1, wc = wave & 1;     // wave tile 32 x 64
    const int l4 = lane >> 4, lc = lane & 15;
    const int brow = blockIdx.y * BM;
    const int bcol = blockIdx.x * BN;
    const size_t aT0 = (size_t)(brow >> 6) * NT;
    const size_t bT0 = (size_t)(bcol >> 7) * NT;

    // precompute the 12 per-wave staging sources (chunk-linear: +lane*16B)
    const _Float16* srcb[12];
    int str[12];
#pragma unroll
    for (int i = 0; i < 12; ++i) {
        int c = wave * 12 + i;
        if (c < 8)       { srcb[i] = Ahi  + aT0 * TA + c * 512;        str[i] = TA; }
        else if (c < 16) { srcb[i] = Alo  + aT0 * TA + (c - 8) * 512;  str[i] = TA; }
        else if (c < 32) { srcb[i] = BThi + bT0 * TB + (c - 16) * 512; str[i] = TB; }
        else             { srcb[i] = BTlo + bT0 * TB + (c - 32) * 512; str[i] = TB; }
        srcb[i] += lane * 8;
    }

    auto stage = [&](int buf, int t) {
#pragma unroll
        for (int i = 0; i < 12; ++i)
            GLD_LDS16(srcb[i] + (size_t)t * str[i], &ring[buf][(wave * 12 + i) * 512]);
    };

    f32x4 acc[2][4];
#pragma unroll
    for (int mi = 0; mi < 2; ++mi)
#pragma unroll
        for (int ni = 0; ni < 4; ++ni)
#pragma unroll
            for (int c = 0; c < 4; ++c) acc[mi][ni][c] = 0.f;

    stage(0, 0);
    stage(1, 1);

#pragma unroll
    for (int t = 0; t < NT; ++t) {
        // counted wait: stage(t)'s 12 loads done (stage(t+1)'s may stay in flight)
        if (t < NT - 1) asm volatile("s_waitcnt vmcnt(12)" ::: "memory");
        else            asm volatile("s_waitcnt vmcnt(0)" ::: "memory");
        __builtin_amdgcn_s_barrier();           // all waves' tile-t loads visible
        __builtin_amdgcn_sched_barrier(0);
        const _Float16* L = ring[t % 3];
#pragma unroll
        for (int ks = 0; ks < 2; ++ks) {
            h8 ah[2], al[2], bh[4], bl[4];
#pragma unroll
            for (int mi = 0; mi < 2; ++mi) {
                int mf = wr * 2 + mi;
                ah[mi] = *(const h8*)&L[(mf * 2 + ks) * 512 + lane * 8];
                al[mi] = *(const h8*)&L[(8 + mf * 2 + ks) * 512 + lane * 8];
            }
#pragma unroll
            for (int ni = 0; ni < 4; ++ni) {
                int nf = wc * 4 + ni;
                bh[ni] = *(const h8*)&L[(16 + nf * 2 + ks) * 512 + lane * 8];
                bl[ni] = *(const h8*)&L[(32 + nf * 2 + ks) * 512 + lane * 8];
            }
#pragma unroll
            for (int mi = 0; mi < 2; ++mi)
#pragma unroll
                for (int ni = 0; ni < 4; ++ni) {
                    acc[mi][ni] = __builtin_amdgcn_mfma_f32_16x16x32_f16(
                        ah[mi], bh[ni], acc[mi][ni], 0, 0, 0);
                    acc[mi][ni] = __builtin_amdgcn_mfma_f32_16x16x32_f16(
                        al[mi], bh[ni], acc[mi][ni], 0, 0, 0);
                    acc[mi][ni] = __builtin_amdgcn_mfma_f32_16x16x32_f16(
                        ah[mi], bl[ni], acc[mi][ni], 0, 0, 0);
                }
        }
        if (t + 2 < NT) stage((t + 2) % 3, t + 2);   // after barrier: WAR-safe
    }

    __syncthreads();                         // loop done; safe to alias LDS
    float* sR = (float*)&ring[0][0];         // [2][8][128] = 8KB
    float* nL = (float*)((char*)sR + 8192);  // [64][2] row-norm partials

    float bv[4];
#pragma unroll
    for (int ni = 0; ni < 4; ++ni) bv[ni] = bias[bcol + wc * 64 + ni * 16 + lc];

    if constexpr (EPI == 0) {
        const int half = (brow >= BATCH) ? 1 : 0;
        float s[4] = {}, q[4] = {};
#pragma unroll
        for (int mi = 0; mi < 2; ++mi)
#pragma unroll
            for (int j = 0; j < 4; ++j) {
                int gr = brow + wr * 32 + mi * 16 + l4 * 4 + j;
#pragma unroll
                for (int ni = 0; ni < 4; ++ni) {
                    float v = acc[mi][ni][j] + bv[ni];
                    Cout[(size_t)gr * N + bcol + wc * 64 + ni * 16 + lc] = v;
                    s[ni] += v;
                    q[ni] = fmaf(v, v, q[ni]);
                }
            }
#pragma unroll
        for (int ni = 0; ni < 4; ++ni) {
            sR[(wr * 4 + l4) * 128 + wc * 64 + ni * 16 + lc] = s[ni];
            sR[1024 + (wr * 4 + l4) * 128 + wc * 64 + ni * 16 + lc] = q[ni];
        }
        __syncthreads();
        if (tid < BN) {
            float ss = 0.f, qq = 0.f;
#pragma unroll
            for (int i = 0; i < 8; ++i) {
                ss += sR[i * 128 + tid];
                qq += sR[1024 + i * 128 + tid];
            }
            atomicAdd(&red[half * 512 + bcol + tid], ss);
            atomicAdd(&red[half * 512 + 256 + bcol + tid], qq);
        }
    } else {
        float v[2][4][4];                    // [mi][j][ni]
#pragma unroll
        for (int mi = 0; mi < 2; ++mi)
#pragma unroll
            for (int j = 0; j < 4; ++j) {
                float ssq = 0.f;
#pragma unroll
                for (int ni = 0; ni < 4; ++ni) {
                    v[mi][j][ni] = acc[mi][ni][j] + bv[ni];
                    ssq = fmaf(v[mi][j][ni], v[mi][j][ni], ssq);
                }
#pragma unroll
                for (int o = 1; o < 16; o <<= 1) ssq += __shfl_xor(ssq, o);
                if (lc == 0) nL[(wr * 32 + mi * 16 + l4 * 4 + j) * 2 + wc] = ssq;
            }
        __syncthreads();
        float s[4] = {};
#pragma unroll
        for (int mi = 0; mi < 2; ++mi)
#pragma unroll
            for (int j = 0; j < 4; ++j) {
                int lrow = wr * 32 + mi * 16 + l4 * 4 + j;
                float tot = nL[lrow * 2] + nL[lrow * 2 + 1];
                float inv = 1.0f / fmaxf(sqrtf(tot), 1e-12f);
#pragma unroll
                for (int ni = 0; ni < 4; ++ni) {
                    float z = v[mi][j][ni] * inv;
                    Cout[(size_t)(brow + lrow) * DOUT + wc * 64 + ni * 16 + lc] = z;
                    s[ni] += z;
                }
            }
        __syncthreads();
#pragma unroll
        for (int ni = 0; ni < 4; ++ni)
            sR[(wr * 4 + l4) * 128 + wc * 64 + ni * 16 + lc] = s[ni];
        __syncthreads();
        if (tid < BN) {
            float ss = 0.f;
#pragma unroll
            for (int i = 0; i < 8; ++i) ss += sR[i * 128 + tid];
            atomicAdd(&red[tid], ss);
        }
    }
}

// tiled-dest index helpers (halfs). KT = K/64 of the destination operand.
__device__ __forceinline__ size_t tiledA(int r, int k, int KT) {
    return (size_t)((r >> 6) * KT + (k >> 6)) * 4096 +
           ((((r & 63) >> 4) * 2 + ((k & 63) >> 5)) * 512) +
           (((r & 15) | (((k & 31) >> 3) << 4)) * 8) + (k & 7);
}
__device__ __forceinline__ size_t tiledB(int n, int k, int KT) {
    return (size_t)((n >> 7) * KT + (k >> 6)) * 8192 +
           ((((n & 127) >> 4) * 2 + ((k & 63) >> 5)) * 512) +
           (((n & 15) | (((k & 31) >> 3) << 4)) * 8) + (k & 7);
}

// ---------------------------------------------------------------------------
// Prep: split [x1;x2] -> tiled Xhi/Xlo, W1/W2/W3 -> tiled transposed hi/lo.
// Blocks [0,2048): X.  Blocks [2048,2272): W.
// ---------------------------------------------------------------------------
__global__ __launch_bounds__(256) void split_xw(
    const float* __restrict__ x1, const float* __restrict__ x2,
    const float* __restrict__ W1, const float* __restrict__ W2,
    const float* __restrict__ W3,
    _Float16* __restrict__ Xhi, _Float16* __restrict__ Xlo,
    _Float16* __restrict__ W1hiT, _Float16* __restrict__ W1loT,
    _Float16* __restrict__ W2hiT, _Float16* __restrict__ W2loT,
    _Float16* __restrict__ W3hiT, _Float16* __restrict__ W3loT)
{
    const int b = blockIdx.x;
    if (b < 2048) {
        const float* src = (b < 1024) ? x1 : x2;
        const int rbase = (b < 1024) ? 0 : BATCH;
#pragma unroll
        for (int i = 0; i < 4; ++i) {
            size_t f = (size_t)(b & 1023) * 1024 + i * 256 + threadIdx.x;
            int r = rbase + (int)(f >> 7);
            int c0 = ((int)f & 127) << 2;
            f4 vv = ((const f4*)src)[f];
            h4 hi, lo;
#pragma unroll
            for (int j = 0; j < 4; ++j) {
                hi[j] = (_Float16)vv[j];
                lo[j] = (_Float16)(vv[j] - (float)hi[j]);
            }
            size_t d = tiledA(r, c0, DIN / 64);
            *(h4*)&Xhi[d] = hi;
            *(h4*)&Xlo[d] = lo;
        }
    } else {
        const int wb = b - 2048;
#pragma unroll
        for (int i = 0; i < 4; ++i) {
            int e = wb * 1024 + i * 256 + threadIdx.x;   // 0..229375
            if (e < 131072) {                 // W1: K=512, N=256
                int n = e >> 9, k = e & 511;
                float w = W1[(size_t)k * 256 + n];
                _Float16 hi = (_Float16)w;
                size_t d = tiledB(n, k, 8);
                W1hiT[d] = hi; W1loT[d] = (_Float16)(w - (float)hi);
            } else if (e < 196608) {          // W2: K=256, N=256
                int r = e - 131072;
                int n = r >> 8, k = r & 255;
                float w = W2[(size_t)k * 256 + n];
                _Float16 hi = (_Float16)w;
                size_t d = tiledB(n, k, 4);
                W2hiT[d] = hi; W2loT[d] = (_Float16)(w - (float)hi);
            } else {                          // W3: K=256, N=128
                int r = e - 196608;
                int n = r >> 8, k = r & 255;
                float w = W3[(size_t)k * 128 + n];
                _Float16 hi = (_Float16)w;
                size_t d = tiledB(n, k, 4);
                W3hiT[d] = hi; W3loT[d] = (_Float16)(w - (float)hi);
            }
        }
    }
}

// ---------------------------------------------------------------------------
// BN apply + ReLU + hi/lo split, writing TILED H (next GEMM's A operand).
// Block = 64 rows; thread owns a fixed f4 column; 16 coalesced row-iters.
// ---------------------------------------------------------------------------
__global__ __launch_bounds__(256) void bnrelu_split(
    const float* __restrict__ Y, const float* __restrict__ stats,
    const float* __restrict__ g, const float* __restrict__ beta,
    _Float16* __restrict__ Hhi, _Float16* __restrict__ Hlo)
{
    const int c0 = (threadIdx.x & 63) << 2;
    const int rj = threadIdx.x >> 6;
    const int row0 = blockIdx.x * 64;
    const int half = (row0 >= BATCH) ? 1 : 0;
    const float invN = 1.0f / (float)BATCH;
    f4 sc, sh;
#pragma unroll
    for (int j = 0; j < 4; ++j) {
        int c = c0 + j;
        float mu = stats[half * 512 + c] * invN;
        float var = fmaf(-mu, mu, stats[half * 512 + 256 + c] * invN);
        float s = g[c] * rsqrtf(var + EPS_BN);
        sc[j] = s;
        sh[j] = fmaf(-mu, s, beta[c]);
    }
#pragma unroll 4
    for (int it = 0; it < 16; ++it) {
        int row = row0 + it * 4 + rj;
        f4 v = *(const f4*)(Y + (size_t)row * DH + c0);
        h4 hi, lo;
#pragma unroll
        for (int j = 0; j < 4; ++j) {
            float h = fmaxf(fmaf(v[j], sc[j], sh[j]), 0.f);
            hi[j] = (_Float16)h;
            lo[j] = (_Float16)(h - (float)hi[j]);
        }
        size_t d = tiledA(row, c0, DH / 64);
        *(h4*)&Hhi[d] = hi;
        *(h4*)&Hlo[d] = lo;
    }
}

// ---------------------------------------------------------------------------
// Fused positives + loss. 64-lane group handles pair (i, i+B).
// ---------------------------------------------------------------------------
__global__ __launch_bounds__(256) void losspos(const float* __restrict__ reps,
                                               const float* __restrict__ Svec,
                                               float* __restrict__ out)
{
    const int lane = threadIdx.x & 63;
    const int grp = threadIdx.x >> 6;
    __shared__ float part[4];
    float2 sv = ((const float2*)Svec)[lane];
    float acc = 0.f;
#pragma unroll 1
    for (int it = 0; it < 8; ++it) {
        int p = blockIdx.x * 32 + it * 4 + grp;
        float2 a = ((const float2*)(reps + (size_t)p * DOUT))[lane];
        float2 b = ((const float2*)(reps + (size_t)(p + BATCH) * DOUT))[lane];
        float dp  = fmaf(a.x, b.x, a.y * b.y);
        float rsA = fmaf(a.x, sv.x, a.y * sv.y);
        float sdA = fmaf(a.x, a.x, a.y * a.y);
        float rsB = fmaf(b.x, sv.x, b.y * sv.y);
        float sdB = fmaf(b.x, b.x, b.y * b.y);
#pragma unroll
        for (int o = 32; o; o >>= 1) {
            dp  += __shfl_xor(dp, o);
            rsA += __shfl_xor(rsA, o);
            sdA += __shfl_xor(sdA, o);
            rsB += __shfl_xor(rsB, o);
            sdB += __shfl_xor(sdB, o);
        }
        if (lane == 0) {
            float nom = expf(dp / TEMP);
            float dA = (rsA - sdA) / TEMP;
            float dB = (rsB - sdB) / TEMP;
            acc += -logf(nom / dA) - logf(nom / dB);
        }
    }
    if (lane == 0) part[grp] = acc;
    __syncthreads();
    if (threadIdx.x == 0) {
        float t = part[0] + part[1] + part[2] + part[3];
        atomicAdd(out, t * (1.0f / (float)MROWS));
    }
}

// zero the accumulators (stats1, stats2, Svec) and the output scalar
__global__ void zero_kernel(float* __restrict__ smalls, float* __restrict__ out)
{
    int i = blockIdx.x * 256 + threadIdx.x;
    if (i < 2176) smalls[i] = 0.f;
    if (i == 0) out[0] = 0.f;
}

extern "C" void kernel_launch(void* const* d_in, const int* in_sizes, int n_in,
                              void* d_out, int out_size, void* d_ws, size_t ws_size,
                              hipStream_t stream)
{
    const float* x1    = (const float*)d_in[0];
    const float* x2    = (const float*)d_in[1];
    const float* W1    = (const float*)d_in[2];
    const float* b1    = (const float*)d_in[3];
    const float* g1    = (const float*)d_in[4];
    const float* beta1 = (const float*)d_in[5];
    const float* W2    = (const float*)d_in[6];
    const float* b2    = (const float*)d_in[7];
    const float* g2    = (const float*)d_in[8];
    const float* beta2 = (const float*)d_in[9];
    const float* W3    = (const float*)d_in[10];
    const float* b3    = (const float*)d_in[11];
    float* out = (float*)d_out;

    // workspace overlay (MiB offsets; every buffer is exactly sized):
    //  [0,16):  Xhi -> H1hi(8)+H1lo(8) -> H2hi(8)+H2lo(8)
    //  [16,32): Xlo -> Y2 -> reps
    //  [32,48): Y1
    //  [48,..): tiled W splits (896KB) + smalls
    char* W = (char*)d_ws;
    _Float16* XHI  = (_Float16*)(W);
    _Float16* XLO  = (_Float16*)(W + (16u << 20));
    float*    Y1   = (float*)   (W + (32u << 20));
    _Float16* H1HI = (_Float16*)(W);
    _Float16* H1LO = (_Float16*)(W + (8u << 20));
    float*    Y2   = (float*)   (W + (16u << 20));
    _Float16* H2HI = (_Float16*)(W);
    _Float16* H2LO = (_Float16*)(W + (8u << 20));
    float*    REPS = (float*)   (W + (16u << 20));
    char* wb = W + (48u << 20);
    _Float16* W1HIT = (_Float16*)(wb);
    _Float16* W1LOT = (_Float16*)(wb + 262144);
    _Float16* W2HIT = (_Float16*)(wb + 524288);
    _Float16* W2LOT = (_Float16*)(wb + 655360);
    _Float16* W3HIT = (_Float16*)(wb + 786432);
    _Float16* W3LOT = (_Float16*)(wb + 851968);
    float* smalls   = (float*)  (wb + 917504);
    float* stats1 = smalls;
    float* stats2 = smalls + 1024;
    float* Svec   = smalls + 2048;

    zero_kernel<<<9, 256, 0, stream>>>(smalls, out);

    // prep: tiled X hi/lo + tiled transposed W hi/lo
    split_xw<<<2272, 256, 0, stream>>>(x1, x2, W1, W2, W3, XHI, XLO,
                                       W1HIT, W1LOT, W2HIT, W2LOT, W3HIT, W3LOT);

    // L1: X @ W1 + b1 -> Y1 (+stats1)
    gemm3h<DIN, DH, 0><<<dim3(DH / 128, MROWS / 64), 256, 0, stream>>>(
        XHI, XLO, W1HIT, W1LOT, b1, Y1, stats1);
    bnrelu_split<<<MROWS / 64, 256, 0, stream>>>(Y1, stats1, g1, beta1, H1HI, H1LO);

    // L2: H1 @ W2 + b2 -> Y2 (+stats2)
    gemm3h<DH, DH, 0><<<dim3(DH / 128, MROWS / 64), 256, 0, stream>>>(
        H1HI, H1LO, W2HIT, W2LOT, b2, Y2, stats2);
    bnrelu_split<<<MROWS / 64, 256, 0, stream>>>(Y2, stats2, g2, beta2, H2HI, H2LO);

    // L3: H2 @ W3 + b3 -> row-normalized reps (+Svec)
    gemm3h<DH, DOUT, 1><<<dim3(DOUT / 128, MROWS / 64), 256, 0, stream>>>(
        H2HI, H2LO, W3HIT, W3LOT, b3, REPS, Svec);

    // positives + loss
    losspos<<<BATCH / 32, 256, 0, stream>>>(REPS, Svec, out);
}

// Round 6
// 166.692 us; speedup vs baseline: 4.0229x; 1.1431x over previous
//
#include <hip/hip_runtime.h>
#include <math.h>

// Problem constants (from reference)
#define BATCH   8192
#define MROWS   16384      // 2*BATCH rows processed through the MLP
#define DIN     512
#define DH      256
#define DOUT    128
#define EPS_BN  1e-5f
#define TEMP    0.07f

using f4    = __attribute__((ext_vector_type(4))) float;
using f32x4 = __attribute__((ext_vector_type(4))) float;
using h4    = __attribute__((ext_vector_type(4))) _Float16;
using h8    = __attribute__((ext_vector_type(8))) _Float16;

// async global->LDS, 16B per lane: per-lane GLOBAL src, wave-uniform LDS base
#define GLD_LDS16(gp, lp) __builtin_amdgcn_global_load_lds( \
    (const __attribute__((address_space(1))) void*)(gp),    \
    (__attribute__((address_space(3))) void*)(lp), 16, 0, 0)

// ---------------------------------------------------------------------------
// Fully-fused fp16x3 GEMM:
//   C = f(A) @ B + bias,  f = identity (FUSE_BN=0, A = [x1;x2] fp32)
//                         f = BN-affine+ReLU (FUSE_BN=1, A = Y fp32, stats/g/beta)
//   A@B via fp16 hi/lo 3-term split: Ahi.Bhi + Alo.Bhi + Ahi.Blo
// A is REGISTER-staged from fp32 (2xf4/thread/tile), processed (affine+relu),
// split hi/lo, ds_write'd into frag-linear LDS.  B (pre-split transposed W)
// staged via global_load_lds.  BK=32, ring-3 LDS (A 24KB + B 48KB + scsh 2KB
// = 74KB -> 2 blocks/CU), one raw s_barrier per tile, counted vmcnt (never 0
// mid-loop).  Counted waits only require the NEEDED loads to be oldest, so
// stray compiler-issued loads can't break correctness.
// Tiles BM=64 BN=128; 4 waves (2x2), wave-tile 32x64; mfma_f32_16x16x32_f16
// (frag mappings HW-verified by rounds 4-5: A/B lane l: row|col=l&15,
//  k=(l>>4)*8+j; C lane l: col=l&15, row=(l>>4)*4+reg).
// EPI=0: store C + per-col BN stats (atomics). EPI=1: rownorm + reps + Svec.
// Grid is 1-D: by=wg&255 (row tile), bx=wg>>8 (col tile) -> the two col-tiles
// of the same rows are 256 apart == same XCD (256%8==0) -> A re-read hits L2.
// ---------------------------------------------------------------------------
template <int K, int N, int FUSE_BN, int EPI>
__global__ __launch_bounds__(256, 2) void gemm_fused(
    const float* __restrict__ A1, const float* __restrict__ A2, int splitRow,
    const _Float16* __restrict__ BThi, const _Float16* __restrict__ BTlo,
    const float* __restrict__ stats, const float* __restrict__ g,
    const float* __restrict__ beta, const float* __restrict__ bias,
    float* __restrict__ Cout, float* __restrict__ red)
{
    constexpr int NT = K / 32;               // 32-k tiles

    const int tid = threadIdx.x;
    const int wave = tid >> 6, lane = tid & 63;
    const int wr = wave >> 1, wc = wave & 1;
    const int l4 = lane >> 4, lc = lane & 15;
    const int wg = blockIdx.x;
    const int brow = (wg & 255) * 64;
    const int bcol = (wg >> 8) * 128;
    const int half = (brow >= BATCH) ? 1 : 0;

    __shared__ __align__(16) char smem[75776];
    _Float16* Bring = (_Float16*)smem;             // [3][8192]: hi 8 frags, lo 8
    _Float16* Aring = (_Float16*)(smem + 49152);   // [3][4096]: hi 4 frags, lo 4
    float*    scsh  = (float*)(smem + 73728);      // sc[256], sh[256]
    float*    sR    = (float*)(smem + 49152);      // epilogue alias (8KB)
    float*    nLp   = (float*)(smem + 49152 + 8192);

    // ---- B staging: wave w handles frags {2w, 2w+1} of Bhi and Blo ----
    const _Float16* bsrc[4];
    {
        const int co = (bcol + wave * 32 + lc) * K + l4 * 8;
        bsrc[0] = BThi + co;
        bsrc[1] = BThi + co + 16 * K;
        bsrc[2] = BTlo + co;
        bsrc[3] = BTlo + co + 16 * K;
    }
    auto stageB = [&](int buf, int t) {
        _Float16* d = Bring + buf * 8192 + wave * 1024;
        GLD_LDS16(bsrc[0] + t * 32, d);
        GLD_LDS16(bsrc[1] + t * 32, d + 512);
        GLD_LDS16(bsrc[2] + t * 32, d + 4096);
        GLD_LDS16(bsrc[3] + t * 32, d + 4096 + 512);
    };

    // ---- A staging: wave w = frag w; lane l: row=w*16+(l&15), k0=(l>>4)*8.
    // The 4 lanes {lc, lc+16, lc+32, lc+48} read one full 128B line of a row.
    const int arow = wave * 16 + lc;
    const int ak0 = l4 * 8;
    const int growA = brow + arow;
    const float* asrc = (growA < splitRow)
        ? (A1 + (size_t)growA * K + ak0)
        : (A2 + (size_t)(growA - splitRow) * K + ak0);

    f4 ar[2][2];
    auto loadA = [&](int p, int t) {
        ar[p][0] = *(const f4*)(asrc + t * 32);
        ar[p][1] = *(const f4*)(asrc + t * 32 + 4);
    };
    auto procA = [&](int p, int buf, int t) {
        float v[8];
#pragma unroll
        for (int j = 0; j < 4; ++j) { v[j] = ar[p][0][j]; v[4 + j] = ar[p][1][j]; }
        if constexpr (FUSE_BN) {
            f4 s0 = *(const f4*)&scsh[t * 32 + ak0];
            f4 s1 = *(const f4*)&scsh[t * 32 + ak0 + 4];
            f4 h0 = *(const f4*)&scsh[256 + t * 32 + ak0];
            f4 h1 = *(const f4*)&scsh[256 + t * 32 + ak0 + 4];
#pragma unroll
            for (int j = 0; j < 4; ++j) {
                v[j]     = fmaxf(fmaf(v[j],     s0[j], h0[j]), 0.f);
                v[4 + j] = fmaxf(fmaf(v[4 + j], s1[j], h1[j]), 0.f);
            }
        }
        h8 hi, lo;
#pragma unroll
        for (int j = 0; j < 8; ++j) {
            _Float16 h = (_Float16)v[j];
            hi[j] = h;
            lo[j] = (_Float16)(v[j] - (float)h);
        }
        _Float16* d = Aring + buf * 4096 + wave * 512 + lane * 8;
        *(h8*)d = hi;
        *(h8*)(d + 2048) = lo;
    };

    f32x4 acc[2][4];
#pragma unroll
    for (int mi = 0; mi < 2; ++mi)
#pragma unroll
        for (int ni = 0; ni < 4; ++ni)
#pragma unroll
            for (int c = 0; c < 4; ++c) acc[mi][ni][c] = 0.f;

    auto compute = [&](int buf) {
        const _Float16* Ab = Aring + buf * 4096;
        const _Float16* Bb = Bring + buf * 8192;
        h8 ah[2], al[2], bh[4], bl[4];
#pragma unroll
        for (int mi = 0; mi < 2; ++mi) {
            ah[mi] = *(const h8*)(Ab + (wr * 2 + mi) * 512 + lane * 8);
            al[mi] = *(const h8*)(Ab + 2048 + (wr * 2 + mi) * 512 + lane * 8);
        }
#pragma unroll
        for (int ni = 0; ni < 4; ++ni) {
            bh[ni] = *(const h8*)(Bb + (wc * 4 + ni) * 512 + lane * 8);
            bl[ni] = *(const h8*)(Bb + 4096 + (wc * 4 + ni) * 512 + lane * 8);
        }
#pragma unroll
        for (int mi = 0; mi < 2; ++mi)
#pragma unroll
            for (int ni = 0; ni < 4; ++ni) {
                acc[mi][ni] = __builtin_amdgcn_mfma_f32_16x16x32_f16(
                    ah[mi], bh[ni], acc[mi][ni], 0, 0, 0);
                acc[mi][ni] = __builtin_amdgcn_mfma_f32_16x16x32_f16(
                    al[mi], bh[ni], acc[mi][ni], 0, 0, 0);
                acc[mi][ni] = __builtin_amdgcn_mfma_f32_16x16x32_f16(
                    ah[mi], bl[ni], acc[mi][ni], 0, 0, 0);
            }
    };

    // ---- prologue ----
    if constexpr (FUSE_BN) {
        const float invN = 1.0f / (float)BATCH;
        float mu = stats[half * 512 + tid] * invN;
        float var = fmaf(-mu, mu, stats[half * 512 + 256 + tid] * invN);
        float s = g[tid] * rsqrtf(var + EPS_BN);
        scsh[tid] = s;
        scsh[256 + tid] = fmaf(-mu, s, beta[tid]);
    }
    loadA(0, 0);
    stageB(0, 0);
    stageB(1, 1);
    if constexpr (FUSE_BN) {               // scsh visible before procA reads it
        asm volatile("s_waitcnt lgkmcnt(0)" ::: "memory");
        __builtin_amdgcn_s_barrier();
    }
    procA(0, 0, 0);                        // compiler waits ar[0]'s own vmcnt
    loadA(1, 1);
    asm volatile("s_waitcnt vmcnt(6)" ::: "memory");   // B(0) done; B(1)+ar(1) fly
    asm volatile("s_waitcnt lgkmcnt(0)" ::: "memory"); // A[0] ds_writes done
    __builtin_amdgcn_s_barrier();

    // ---- main loop: one raw barrier per tile, counted vmcnt ----
#pragma unroll
    for (int t = 0; t < NT; ++t) {
        if (t + 2 < NT) stageB((t + 2) % 3, t + 2);
        compute(t % 3);
        if (t + 1 < NT) {
            if (t + 2 < NT) asm volatile("s_waitcnt vmcnt(4)" ::: "memory");
            else            asm volatile("s_waitcnt vmcnt(0)" ::: "memory");
            __builtin_amdgcn_sched_barrier(0);
            procA((t + 1) & 1, (t + 1) % 3, t + 1);
            if (t + 2 < NT) loadA(t & 1, t + 2);
        }
        asm volatile("s_waitcnt lgkmcnt(0)" ::: "memory");
        __builtin_amdgcn_s_barrier();
    }
    __syncthreads();                        // all waves done -> alias Aring

    // ---- epilogue ----
    float bv[4];
#pragma unroll
    for (int ni = 0; ni < 4; ++ni) bv[ni] = bias[bcol + wc * 64 + ni * 16 + lc];

    if constexpr (EPI == 0) {
        float s[4] = {}, q[4] = {};
#pragma unroll
        for (int mi = 0; mi < 2; ++mi)
#pragma unroll
            for (int j = 0; j < 4; ++j) {
                int gr = brow + wr * 32 + mi * 16 + l4 * 4 + j;
#pragma unroll
                for (int ni = 0; ni < 4; ++ni) {
                    float v = acc[mi][ni][j] + bv[ni];
                    Cout[(size_t)gr * N + bcol + wc * 64 + ni * 16 + lc] = v;
                    s[ni] += v;
                    q[ni] = fmaf(v, v, q[ni]);
                }
            }
#pragma unroll
        for (int ni = 0; ni < 4; ++ni) {
            sR[(wr * 4 + l4) * 128 + wc * 64 + ni * 16 + lc] = s[ni];
            sR[1024 + (wr * 4 + l4) * 128 + wc * 64 + ni * 16 + lc] = q[ni];
        }
        __syncthreads();
        if (tid < 128) {
            float ss = 0.f, qq = 0.f;
#pragma unroll
            for (int i = 0; i < 8; ++i) {
                ss += sR[i * 128 + tid];
                qq += sR[1024 + i * 128 + tid];
            }
            atomicAdd(&red[half * 512 + bcol + tid], ss);
            atomicAdd(&red[half * 512 + 256 + bcol + tid], qq);
        }
    } else {
        float v[2][4][4];                   // [mi][j][ni]
#pragma unroll
        for (int mi = 0; mi < 2; ++mi)
#pragma unroll
            for (int j = 0; j < 4; ++j) {
                float ssq = 0.f;
#pragma unroll
                for (int ni = 0; ni < 4; ++ni) {
                    v[mi][j][ni] = acc[mi][ni][j] + bv[ni];
                    ssq = fmaf(v[mi][j][ni], v[mi][j][ni], ssq);
                }
#pragma unroll
                for (int o = 1; o < 16; o <<= 1) ssq += __shfl_xor(ssq, o);
                if (lc == 0) nLp[(wr * 32 + mi * 16 + l4 * 4 + j) * 2 + wc] = ssq;
            }
        __syncthreads();
        float s[4] = {};
#pragma unroll
        for (int mi = 0; mi < 2; ++mi)
#pragma unroll
            for (int j = 0; j < 4; ++j) {
                int lrow = wr * 32 + mi * 16 + l4 * 4 + j;
                float tot = nLp[lrow * 2] + nLp[lrow * 2 + 1];
                float inv = 1.0f / fmaxf(sqrtf(tot), 1e-12f);
#pragma unroll
                for (int ni = 0; ni < 4; ++ni) {
                    float z = v[mi][j][ni] * inv;
                    Cout[(size_t)(brow + lrow) * DOUT + wc * 64 + ni * 16 + lc] = z;
                    s[ni] += z;
                }
            }
        __syncthreads();
#pragma unroll
        for (int ni = 0; ni < 4; ++ni)
            sR[(wr * 4 + l4) * 128 + wc * 64 + ni * 16 + lc] = s[ni];
        __syncthreads();
        if (tid < 128) {
            float ss = 0.f;
#pragma unroll
            for (int i = 0; i < 8; ++i) ss += sR[i * 128 + tid];
            atomicAdd(&red[tid], ss);
        }
    }
}

// ---------------------------------------------------------------------------
// W prep (hi/lo split, transposed row-major [n][k]) + zeroing block.
// Coalesced reads (consecutive threads -> consecutive n); h4 writes.
// ---------------------------------------------------------------------------
__global__ __launch_bounds__(256) void wprep(
    const float* __restrict__ W1, const float* __restrict__ W2,
    const float* __restrict__ W3,
    _Float16* __restrict__ W1hiT, _Float16* __restrict__ W1loT,
    _Float16* __restrict__ W2hiT, _Float16* __restrict__ W2loT,
    _Float16* __restrict__ W3hiT, _Float16* __restrict__ W3loT,
    float* __restrict__ smalls, float* __restrict__ out)
{
    const int b = blockIdx.x;
    if (b == 56) {
        for (int i = threadIdx.x; i < 2176; i += 256) smalls[i] = 0.f;
        if (threadIdx.x == 0) out[0] = 0.f;
        return;
    }
#pragma unroll
    for (int i = 0; i < 4; ++i) {
        int qd = b * 1024 + i * 256 + threadIdx.x;   // quad index, < 57344
        const float* src; _Float16 *dhi, *dlo; int n, kq, Nw, Kw;
        if (qd < 32768)      { src = W1; dhi = W1hiT; dlo = W1loT;
                               n = qd & 255;            kq = qd >> 8; Nw = 256; Kw = 512; }
        else if (qd < 49152) { src = W2; dhi = W2hiT; dlo = W2loT;
                               n = (qd - 32768) & 255;  kq = (qd - 32768) >> 8; Nw = 256; Kw = 256; }
        else                 { src = W3; dhi = W3hiT; dlo = W3loT;
                               n = (qd - 49152) & 127;  kq = (qd - 49152) >> 7; Nw = 128; Kw = 256; }
        h4 hi, lo;
#pragma unroll
        for (int j = 0; j < 4; ++j) {
            float w = src[(size_t)(kq * 4 + j) * Nw + n];
            _Float16 h = (_Float16)w;
            hi[j] = h;
            lo[j] = (_Float16)(w - (float)h);
        }
        *(h4*)&dhi[(size_t)n * Kw + kq * 4] = hi;
        *(h4*)&dlo[(size_t)n * Kw + kq * 4] = lo;
    }
}

// ---------------------------------------------------------------------------
// Fused positives + loss. 64-lane group handles pair (i, i+B).
// ---------------------------------------------------------------------------
__global__ __launch_bounds__(256) void losspos(const float* __restrict__ reps,
                                               const float* __restrict__ Svec,
                                               float* __restrict__ out)
{
    const int lane = threadIdx.x & 63;
    const int grp = threadIdx.x >> 6;
    __shared__ float part[4];
    float2 sv = ((const float2*)Svec)[lane];
    float acc = 0.f;
#pragma unroll 1
    for (int it = 0; it < 8; ++it) {
        int p = blockIdx.x * 32 + it * 4 + grp;
        float2 a = ((const float2*)(reps + (size_t)p * DOUT))[lane];
        float2 b = ((const float2*)(reps + (size_t)(p + BATCH) * DOUT))[lane];
        float dp  = fmaf(a.x, b.x, a.y * b.y);
        float rsA = fmaf(a.x, sv.x, a.y * sv.y);
        float sdA = fmaf(a.x, a.x, a.y * a.y);
        float rsB = fmaf(b.x, sv.x, b.y * sv.y);
        float sdB = fmaf(b.x, b.x, b.y * b.y);
#pragma unroll
        for (int o = 32; o; o >>= 1) {
            dp  += __shfl_xor(dp, o);
            rsA += __shfl_xor(rsA, o);
            sdA += __shfl_xor(sdA, o);
            rsB += __shfl_xor(rsB, o);
            sdB += __shfl_xor(sdB, o);
        }
        if (lane == 0) {
            float nom = expf(dp / TEMP);
            float dA = (rsA - sdA) / TEMP;
            float dB = (rsB - sdB) / TEMP;
            acc += -logf(nom / dA) - logf(nom / dB);
        }
    }
    if (lane == 0) part[grp] = acc;
    __syncthreads();
    if (threadIdx.x == 0) {
        float t = part[0] + part[1] + part[2] + part[3];
        atomicAdd(out, t * (1.0f / (float)MROWS));
    }
}

extern "C" void kernel_launch(void* const* d_in, const int* in_sizes, int n_in,
                              void* d_out, int out_size, void* d_ws, size_t ws_size,
                              hipStream_t stream)
{
    const float* x1    = (const float*)d_in[0];
    const float* x2    = (const float*)d_in[1];
    const float* W1    = (const float*)d_in[2];
    const float* b1    = (const float*)d_in[3];
    const float* g1    = (const float*)d_in[4];
    const float* beta1 = (const float*)d_in[5];
    const float* W2    = (const float*)d_in[6];
    const float* b2    = (const float*)d_in[7];
    const float* g2    = (const float*)d_in[8];
    const float* beta2 = (const float*)d_in[9];
    const float* W3    = (const float*)d_in[10];
    const float* b3    = (const float*)d_in[11];
    float* out = (float*)d_out;

    // workspace: Y1 @0 (16MB), Y2 @16M (16MB), reps @32M (8MB),
    // W splits @40M (896KB), smalls after.
    char* W = (char*)d_ws;
    float*    Y1   = (float*)(W);
    float*    Y2   = (float*)(W + (16u << 20));
    float*    REPS = (float*)(W + (32u << 20));
    char* wb = W + (40u << 20);
    _Float16* W1HIT = (_Float16*)(wb);
    _Float16* W1LOT = (_Float16*)(wb + 262144);
    _Float16* W2HIT = (_Float16*)(wb + 524288);
    _Float16* W2LOT = (_Float16*)(wb + 655360);
    _Float16* W3HIT = (_Float16*)(wb + 786432);
    _Float16* W3LOT = (_Float16*)(wb + 851968);
    float* smalls   = (float*)  (wb + 917504);
    float* stats1 = smalls;
    float* stats2 = smalls + 1024;
    float* Svec   = smalls + 2048;

    const int big = 1 << 30;

    // W hi/lo transposed splits + zero accumulators/out (57 blocks)
    wprep<<<57, 256, 0, stream>>>(W1, W2, W3, W1HIT, W1LOT, W2HIT, W2LOT,
                                  W3HIT, W3LOT, smalls, out);

    // L1: [x1;x2] @ W1 + b1 -> Y1 (+stats1); X read + f16-split fused
    gemm_fused<DIN, DH, 0, 0><<<512, 256, 0, stream>>>(
        x1, x2, BATCH, W1HIT, W1LOT, nullptr, nullptr, nullptr, b1, Y1, stats1);

    // L2: relu(bn(Y1)) @ W2 + b2 -> Y2 (+stats2); BN+ReLU+split fused
    gemm_fused<DH, DH, 1, 0><<<512, 256, 0, stream>>>(
        Y1, Y1, big, W2HIT, W2LOT, stats1, g1, beta1, b2, Y2, stats2);

    // L3: relu(bn(Y2)) @ W3 + b3 -> row-normalized reps (+Svec)
    gemm_fused<DH, DOUT, 1, 1><<<256, 256, 0, stream>>>(
        Y2, Y2, big, W3HIT, W3LOT, stats2, g2, beta2, b3, REPS, Svec);

    // positives + loss
    losspos<<<BATCH / 32, 256, 0, stream>>>(REPS, Svec, out);
}